// Round 9
// baseline (3532.581 us; speedup 1.0000x reference)
//
#include <hip/hip_runtime.h>
#include <hip/hip_bf16.h>
#include <math.h>

#define Bn 16
#define Tn 512
#define Dn 1024
#define Hn 8
#define Ln 6
#define Fn 4096
#define HDn 128

typedef __attribute__((ext_vector_type(8))) short short8;
typedef __attribute__((ext_vector_type(4))) float f32x4;

__device__ __forceinline__ float bf2f(unsigned short u){
  union{float f; unsigned int i;} c; c.i = ((unsigned int)u)<<16; return c.f;
}
__device__ __forceinline__ unsigned short f2bf(float f){
  union{float f; unsigned int i;} c; c.f=f;
  unsigned int r = c.i + 0x7fffu + ((c.i>>16)&1u);
  return (unsigned short)(r>>16);
}

#define GLOAD(gp, lp) __builtin_amdgcn_global_load_lds( \
    (const __attribute__((address_space(1))) void*)(const void*)(gp), \
    (__attribute__((address_space(3))) void*)(void*)(lp), 16, 0, 0)

// ---------------- embedding: x[b,t,:] = embed[tok] + pos[t] ----------------
__global__ __launch_bounds__(256) void embed_kernel(
    const int* __restrict__ tok, const float* __restrict__ emb,
    const float* __restrict__ pos, float* __restrict__ x){
  long row = blockIdx.x;                 // b*T + t
  int t = (int)(row & (Tn-1));
  int tk = tok[row];
  int d = threadIdx.x*4;
  float4 e = *(const float4*)(emb + (long)tk*Dn + d);
  float4 p = *(const float4*)(pos + (long)t*Dn + d);
  float4 r; r.x=e.x+p.x; r.y=e.y+p.y; r.z=e.z+p.z; r.w=e.w+p.w;
  *(float4*)(x + row*(long)Dn + d) = r;
}

// ---------------- LayerNorm over D=1024 (one block per row) ----------------
template<int OUTBF>
__global__ __launch_bounds__(256) void ln_kernel(
    const float* __restrict__ x, const float* __restrict__ g,
    const float* __restrict__ b, void* __restrict__ outp){
  long row = blockIdx.x;
  const float* xr = x + row*(long)Dn;
  int tid = threadIdx.x;
  float4 v4 = *(const float4*)(xr + tid*4);
  float s  = v4.x+v4.y+v4.z+v4.w;
  float s2 = v4.x*v4.x + v4.y*v4.y + v4.z*v4.z + v4.w*v4.w;
  #pragma unroll
  for (int o=32;o;o>>=1){ s += __shfl_xor(s,o); s2 += __shfl_xor(s2,o); }
  __shared__ float rs[4], rs2[4];
  int w = tid>>6;
  if ((tid&63)==0){ rs[w]=s; rs2[w]=s2; }
  __syncthreads();
  s  = rs[0]+rs[1]+rs[2]+rs[3];
  s2 = rs2[0]+rs2[1]+rs2[2]+rs2[3];
  float mu  = s*(1.f/Dn);
  float var = s2*(1.f/Dn) - mu*mu;
  float rstd = rsqrtf(var + 1e-5f);
  float4 gg = *(const float4*)(g + tid*4);
  float4 bb = *(const float4*)(b + tid*4);
  float o0 = (v4.x-mu)*rstd*gg.x + bb.x;
  float o1 = (v4.y-mu)*rstd*gg.y + bb.y;
  float o2 = (v4.z-mu)*rstd*gg.z + bb.z;
  float o3 = (v4.w-mu)*rstd*gg.w + bb.w;
  if (OUTBF){
    unsigned short* o = (unsigned short*)outp + row*(long)Dn + tid*4;
    o[0]=f2bf(o0); o[1]=f2bf(o1); o[2]=f2bf(o2); o[3]=f2bf(o3);
  } else {
    float* o = (float*)outp + row*(long)Dn + tid*4;
    o[0]=o0; o[1]=o1; o[2]=o2; o[3]=o3;
  }
}

// ------------- weight transpose+convert: W[K][N] f32 -> WT[N][K] bf16 -------
__global__ __launch_bounds__(256) void transpose_w(
    const float* __restrict__ W, unsigned short* __restrict__ WT, int Kd, int Nd){
  __shared__ float tile[32][33];
  long lofs = (long)blockIdx.z * Kd * Nd;
  int n0 = blockIdx.x*32, k0 = blockIdx.y*32;
  int tx = threadIdx.x & 31, ty = threadIdx.x >> 5;   // ty 0..7
  #pragma unroll
  for (int i=0;i<4;i++){
    int kk = k0 + ty + i*8;
    tile[ty+i*8][tx] = W[lofs + (long)kk*Nd + n0 + tx];
  }
  __syncthreads();
  #pragma unroll
  for (int i=0;i<4;i++){
    int nn = n0 + ty + i*8;
    WT[lofs + (long)nn*Kd + k0 + tx] = f2bf(tile[tx][ty+i*8]);
  }
}

// ---- pack QKV biases into bqkv[L][3][D] for the batched QKV GEMM ----------
__global__ __launch_bounds__(256) void pack_bias(
    const float* __restrict__ bq, const float* __restrict__ bk,
    const float* __restrict__ bv, float* __restrict__ bqkv){
  int i = blockIdx.x*256 + threadIdx.x;   // l*3*Dn + w*Dn + d
  int l = i / (3*Dn); int r = i - l*3*Dn; int w = r / Dn; int d = r - w*Dn;
  const float* src = (w==0)? bq : ((w==1)? bk : bv);
  bqkv[i] = src[l*Dn + d];
}

// ------- circulant kernel c = irfft(gate per rfft-bin), per (layer,head) ----
__global__ __launch_bounds__(512) void ckern(
    const float* __restrict__ gates, float* __restrict__ cbuf){
  int lh = blockIdx.x;                   // l*H + h
  __shared__ float gb[16];
  if (threadIdx.x < 16) gb[threadIdx.x] = gates[lh*16 + threadIdx.x];
  __syncthreads();
  int m = threadIdx.x;                   // 0..511
  float acc = gb[0];                     // bin 0, weight 1, band 0
  for (int j=1;j<256;j++){
    int band = (j*16)/257;               // (j*BANDS)//nb
    int kmod = (j*m) & 511;              // exact phase reduction
    acc += 2.f*gb[band]*cosf(1.2271846303085129e-2f * (float)kmod); // 2pi/512
  }
  acc += gb[15] * ((m & 1) ? -1.f : 1.f);   // Nyquist bin, band 15
  cbuf[lh*512 + m] = acc * (1.f/512.f);
}

// --------- materialize G[l,h,t,s] = c[(t-s) mod 512] as bf16 ---------------
__global__ __launch_bounds__(256) void gfill(
    const float* __restrict__ cbuf, unsigned short* __restrict__ G){
  long idx = (long)blockIdx.x*256 + threadIdx.x;   // grid sized exactly
  int lh = (int)(idx >> 18);
  int rem = (int)(idx & 262143);
  int t = rem >> 9, s = rem & 511;
  G[idx] = f2bf(cbuf[lh*512 + ((t - s) & 511)]);
}

// --------- pool K,V per head: kp[b,s,d] mean, vTp[b,d,s] mean ---------------
__global__ __launch_bounds__(256) void pool_kernel(
    const unsigned short* __restrict__ kin, const unsigned short* __restrict__ vin,
    unsigned short* __restrict__ kp, unsigned short* __restrict__ vTp){
  long idx = (long)blockIdx.x*256 + threadIdx.x;
  if (idx >= (long)Bn*1920*HDn) return;
  long rem = idx; int hh = 0; int S = 512;
  for (hh=0; hh<8; hh++){
    S = 512 >> (hh>>1);
    long seg = (long)Bn*S*HDn;
    if (rem < seg) break;
    rem -= seg;
  }
  int r = 512 / S;
  int d = (int)(rem % HDn);
  long t2 = rem / HDn;
  int s = (int)(t2 % S);
  int b = (int)(t2 / S);
  const unsigned short* kb = kin + ((long)(b*Tn + s*r))*Dn + hh*HDn + d;
  const unsigned short* vb = vin + ((long)(b*Tn + s*r))*Dn + hh*HDn + d;
  float ks=0.f, vs=0.f;
  for (int j=0;j<r;j++){ ks += bf2f(kb[(long)j*Dn]); vs += bf2f(vb[(long)j*Dn]); }
  float inv = 1.f/(float)r;
  int pref=0;
  for (int g2=0; g2<hh; g2++) pref += 512 >> (g2>>1);
  long segb = (long)Bn*HDn*pref;
  kp [segb + ((long)b*S + s)*HDn + d] = f2bf(ks*inv);
  vTp[segb + ((long)b*HDn + d)*S + s] = f2bf(vs*inv);
}

// --------- row softmax (scale 1/sqrt(128)), fp32 in -> bf16 out -------------
template<int S>
__global__ __launch_bounds__(64) void softmax_kernel(
    const float* __restrict__ sc, unsigned short* __restrict__ at){
  const int NV = S/64;
  long row = blockIdx.x;
  const float* r = sc + row*(long)S;
  int lane = threadIdx.x;
  float vals[NV];
  float mx = -1e30f;
  #pragma unroll
  for (int i=0;i<NV;i++){ vals[i] = r[lane + i*64] * 0.08838834764831845f; mx = fmaxf(mx, vals[i]); }
  #pragma unroll
  for (int o=32;o;o>>=1) mx = fmaxf(mx, __shfl_xor(mx, o));
  float sum = 0.f;
  #pragma unroll
  for (int i=0;i<NV;i++){ vals[i] = expf(vals[i]-mx); sum += vals[i]; }
  #pragma unroll
  for (int o=32;o;o>>=1) sum += __shfl_xor(sum, o);
  float inv = 1.f/sum;
  #pragma unroll
  for (int i=0;i<NV;i++) at[row*(long)S + lane + i*64] = f2bf(vals[i]*inv);
}

// ----------------- generic batched bf16 MFMA GEMM (attention path) ----------
// T3-minimum 2-phase schedule: STAGE(buf^1, t+1) -> ds_read buf[t] -> MFMA
// -> vmcnt(0) -> ONE barrier.  vmcnt(0) drain is covered by the 64-MFMA
// cluster; stage precedes reads so load-issue hides under LDS reads.
template<int MODE>
__global__ __launch_bounds__(256)
void gemm_kernel(const unsigned short* __restrict__ A, int lda, long sAb, long sAh,
                 const unsigned short* __restrict__ Bt, int ldb, long sBb, long sBh,
                 void* __restrict__ Cout, int ldc, long sCb, long sCh,
                 const float* __restrict__ bias, long sbias,
                 int zshift, int zmask,
                 int M, int N, int K)
{
  __shared__ unsigned short AB[2][2][128*64];
  int z = blockIdx.z;
  int zb = z & zmask, zh = z >> zshift;
  const unsigned short* Az = A + (long)zb*sAb + (long)zh*sAh;
  const unsigned short* Bz = Bt + (long)zb*sBb + (long)zh*sBh;
  const float* biasz = bias ? (bias + (long)zh*sbias) : nullptr;
  int m0 = blockIdx.y*128, n0 = blockIdx.x*128;
  int tid = threadIdx.x;
  int lane = tid & 63, wid = tid >> 6;
  int wm = wid >> 1, wn = wid & 1;
  f32x4 zero4 = {0.f,0.f,0.f,0.f};
  f32x4 acc[4][4];
  #pragma unroll
  for (int m=0;m<4;m++)
    #pragma unroll
    for (int n=0;n<4;n++)
      acc[m][n] = zero4;
  const int r16 = lane & 15, kq = lane >> 4;

  auto stage = [&](int buf, int k0){
    #pragma unroll
    for (int i=0;i<4;i++){
      int chunk = i*256 + tid;                 // 1024 chunks of 16B
      int row = chunk >> 3, c = chunk & 7;
      int cg = (c ^ (row & 7)) * 8;            // pre-swizzled global col (elems)
      int gm = m0 + row; gm = gm < M ? gm : M-1;
      GLOAD(Az + (long)gm*lda + k0 + cg, AB[buf][0] + (i*256 + wid*64)*8);
    }
    #pragma unroll
    for (int i=0;i<4;i++){
      int chunk = i*256 + tid;
      int row = chunk >> 3, c = chunk & 7;
      int cg = (c ^ (row & 7)) * 8;
      int gn = n0 + row; gn = gn < N ? gn : N-1;
      GLOAD(Bz + (long)gn*ldb + k0 + cg, AB[buf][1] + (i*256 + wid*64)*8);
    }
  };

  int NT = K >> 6;
  stage(0, 0);
  asm volatile("s_waitcnt vmcnt(0)" ::: "memory");
  __builtin_amdgcn_s_barrier();
  for (int t = 0; t < NT; t++){
    if (t + 1 < NT) stage((t+1)&1, (t+1)*64);
    const unsigned short* As = AB[t&1][0];
    const unsigned short* Bs = AB[t&1][1];
    #pragma unroll
    for (int kk=0; kk<64; kk+=32){
      short8 af[4], bfr[4];
      int kb = (kk + kq*8) * 2;
      #pragma unroll
      for (int m=0;m<4;m++){
        int row = wm*64 + m*16 + r16;
        af[m] = *(const short8*)((const char*)As + row*128 + (kb ^ ((row & 7) << 4)));
      }
      #pragma unroll
      for (int n=0;n<4;n++){
        int row = wn*64 + n*16 + r16;
        bfr[n] = *(const short8*)((const char*)Bs + row*128 + (kb ^ ((row & 7) << 4)));
      }
      __builtin_amdgcn_s_setprio(1);
      #pragma unroll
      for (int m=0;m<4;m++)
        #pragma unroll
        for (int n=0;n<4;n++)
          acc[m][n] = __builtin_amdgcn_mfma_f32_16x16x32_bf16(af[m], bfr[n], acc[m][n], 0, 0, 0);
      __builtin_amdgcn_s_setprio(0);
    }
    if (t + 1 < NT) asm volatile("s_waitcnt vmcnt(0)" ::: "memory");
    __builtin_amdgcn_s_barrier();
  }
  #pragma unroll
  for (int n=0;n<4;n++){
    int col = n0 + wn*64 + n*16 + r16;
    if (col >= N) continue;
    float bvv = 0.f;
    if (MODE != 0 && biasz != nullptr) bvv = biasz[col];
    #pragma unroll
    for (int m=0;m<4;m++){
      #pragma unroll
      for (int e=0;e<4;e++){
        int row = m0 + wm*64 + m*16 + kq*4 + e;
        if (row >= M) continue;
        float vv = acc[m][n][e] + bvv;
        long cidx = (long)zb*sCb + (long)zh*sCh + (long)row*ldc + col;
        if (MODE == 0)      ((float*)Cout)[cidx] = vv;
        else                ((unsigned short*)Cout)[cidx] = f2bf(vv);
      }
    }
  }
}

// ----------------- static-shape 128-tile GEMM (all dense projections) -------
// T3-minimum 2-phase schedule (see gemm_kernel). Natural block order.
// MODE 1: +bias -> bf16 | 2: +bias,GELU -> bf16 | 3: +bias, += into fp32 C
template<int MODE, int Mt, int Nt, int Kt, long SBH, long SCH, int BIASST>
__global__ __launch_bounds__(256)
void gemm_big(const unsigned short* __restrict__ A,
              const unsigned short* __restrict__ Bt,
              void* __restrict__ Cout,
              const float* __restrict__ bias)
{
  __shared__ char shraw[2][32768];              // dbuf: As 16KB + Bs 16KB each
  int zh = blockIdx.z;
  const unsigned short* Bz = Bt + (long)zh*SBH;
  const float* biasz = bias + (long)zh*BIASST;
  int m0 = blockIdx.y*128, n0 = blockIdx.x*128;
  int tid = threadIdx.x;
  int lane = tid & 63, wid = tid >> 6;
  int wm = wid >> 1, wn = wid & 1;
  f32x4 zero4 = {0.f,0.f,0.f,0.f};
  f32x4 acc[4][4];
  #pragma unroll
  for (int m=0;m<4;m++)
    #pragma unroll
    for (int n=0;n<4;n++)
      acc[m][n] = zero4;
  const int r16 = lane & 15, kq = lane >> 4;

  const unsigned short* pA[4];
  const unsigned short* pB[4];
  #pragma unroll
  for (int i=0;i<4;i++){
    int chunk = i*256 + tid;
    int row = chunk >> 3, c = chunk & 7;
    int cg = (c ^ (row & 7)) * 8;
    pA[i] = A  + (long)(m0 + row)*Kt + cg;
    pB[i] = Bz + (long)(n0 + row)*Kt + cg;
  }
  auto stage = [&](int buf, int k0){
    unsigned short* As = (unsigned short*)shraw[buf];
    #pragma unroll
    for (int i=0;i<4;i++) GLOAD(pA[i] + k0, As + (i*256 + wid*64)*8);
    #pragma unroll
    for (int i=0;i<4;i++) GLOAD(pB[i] + k0, As + 8192 + (i*256 + wid*64)*8);
  };

  constexpr int NT = Kt/64;
  stage(0, 0);
  asm volatile("s_waitcnt vmcnt(0)" ::: "memory");
  __builtin_amdgcn_s_barrier();
  for (int t = 0; t < NT; t++){
    if (t + 1 < NT) stage((t+1)&1, (t+1)*64);
    const unsigned short* As = (const unsigned short*)shraw[t&1];
    const unsigned short* Bs = As + 8192;
    #pragma unroll
    for (int kk=0; kk<64; kk+=32){
      short8 af[4], bfr[4];
      int kb = (kk + kq*8) * 2;
      #pragma unroll
      for (int m=0;m<4;m++){
        int row = wm*64 + m*16 + r16;
        af[m] = *(const short8*)((const char*)As + row*128 + (kb ^ ((row & 7) << 4)));
      }
      #pragma unroll
      for (int n=0;n<4;n++){
        int row = wn*64 + n*16 + r16;
        bfr[n] = *(const short8*)((const char*)Bs + row*128 + (kb ^ ((row & 7) << 4)));
      }
      __builtin_amdgcn_s_setprio(1);
      #pragma unroll
      for (int m=0;m<4;m++)
        #pragma unroll
        for (int n=0;n<4;n++)
          acc[m][n] = __builtin_amdgcn_mfma_f32_16x16x32_bf16(af[m], bfr[n], acc[m][n], 0, 0, 0);
      __builtin_amdgcn_s_setprio(0);
    }
    if (t + 1 < NT) asm volatile("s_waitcnt vmcnt(0)" ::: "memory");
    __builtin_amdgcn_s_barrier();
  }

  if (MODE == 1 || MODE == 2){
    // bf16 tile via LDS (stride 136 shorts = 272B = 17*16B, rows 16B-aligned)
    unsigned short* shb = (unsigned short*)&shraw[0][0];
    #pragma unroll
    for (int n=0;n<4;n++){
      int col = wn*64 + n*16 + r16;
      float bvv = biasz[n0 + col];
      #pragma unroll
      for (int m=0;m<4;m++){
        #pragma unroll
        for (int e=0;e<4;e++){
          int row = wm*64 + m*16 + kq*4 + e;
          float vv = acc[m][n][e] + bvv;
          if (MODE == 2) vv = 0.5f*vv*(1.f + erff(vv*0.7071067811865475f));
          shb[row*136 + col] = f2bf(vv);
        }
      }
    }
    __syncthreads();
    // FULL 128x128 tile = 2048 chunks of 8 shorts
    #pragma unroll
    for (int i=0;i<8;i++){
      int chunk = i*256 + tid;
      int row = chunk >> 4, col = (chunk & 15)*8;
      short8 vv8 = *(const short8*)(shb + row*136 + col);
      *(short8*)((unsigned short*)Cout + (long)zh*SCH +
                 (long)(m0 + row)*Nt + n0 + col) = vv8;
    }
  } else {
    // MODE 3: fp32 accumulate, two 64-row phases through LDS (stride 136 floats)
    float* shf = (float*)&shraw[0][0];
    #pragma unroll
    for (int ph=0; ph<2; ph++){
      __syncthreads();
      if (wm == ph){
        #pragma unroll
        for (int n=0;n<4;n++){
          int col = wn*64 + n*16 + r16;
          float bvv = biasz[n0 + col];
          #pragma unroll
          for (int m=0;m<4;m++){
            #pragma unroll
            for (int e=0;e<4;e++){
              int rl = m*16 + kq*4 + e;
              shf[rl*136 + col] = acc[m][n][e] + bvv;
            }
          }
        }
      }
      __syncthreads();
      #pragma unroll
      for (int i=0;i<8;i++){
        int chunk = i*256 + tid;                // 2048 chunks of 4 floats
        int row = chunk >> 5, col = (chunk & 31)*4;
        float4 vv = *(const float4*)(shf + row*136 + col);
        float* cp = (float*)Cout + (long)(m0 + ph*64 + row)*Nt + n0 + col;
        float4 o = *(const float4*)cp;
        o.x += vv.x; o.y += vv.y; o.z += vv.z; o.w += vv.w;
        *(float4*)cp = o;
      }
    }
  }
}

// ---------------------------------------------------------------------------
extern "C" void kernel_launch(void* const* d_in, const int* in_sizes, int n_in,
                              void* d_out, int out_size, void* d_ws, size_t ws_size,
                              hipStream_t stream){
  const int*   tokens = (const int*)  d_in[0];
  const float* embedp = (const float*)d_in[1];
  const float* pos    = (const float*)d_in[2];
  const float* Wq  = (const float*)d_in[3];
  const float* bq  = (const float*)d_in[4];
  const float* Wk  = (const float*)d_in[5];
  const float* bk  = (const float*)d_in[6];
  const float* Wv  = (const float*)d_in[7];
  const float* bv  = (const float*)d_in[8];
  const float* Wo  = (const float*)d_in[9];
  const float* bo  = (const float*)d_in[10];
  const float* ln1g= (const float*)d_in[11];
  const float* ln1b= (const float*)d_in[12];
  const float* ln2g= (const float*)d_in[13];
  const float* ln2b= (const float*)d_in[14];
  const float* W1  = (const float*)d_in[15];
  const float* b1  = (const float*)d_in[16];
  const float* W2  = (const float*)d_in[17];
  const float* b2  = (const float*)d_in[18];
  const float* gates=(const float*)d_in[19];
  const float* lnfg= (const float*)d_in[20];
  const float* lnfb= (const float*)d_in[21];
  float* out = (float*)d_out;

  char* base = (char*)d_ws;
  size_t off = 0;
  auto take = [&](size_t bytes)->char*{
    char* p = base + off;
    off = (off + bytes + 255) & ~(size_t)255;
    return p;
  };
  unsigned short* WqT = (unsigned short*)take((size_t)Ln*Dn*Dn*2);
  unsigned short* WkT = (unsigned short*)take((size_t)Ln*Dn*Dn*2);   // contiguous after WqT
  unsigned short* WvT = (unsigned short*)take((size_t)Ln*Dn*Dn*2);   // contiguous after WkT
  unsigned short* WoT = (unsigned short*)take((size_t)Ln*Dn*Dn*2);
  unsigned short* W1T = (unsigned short*)take((size_t)Ln*Dn*Fn*2);
  unsigned short* W2T = (unsigned short*)take((size_t)Ln*Dn*Fn*2);
  unsigned short* G   = (unsigned short*)take((size_t)Ln*Hn*Tn*Tn*2);
  float*          cbuf= (float*)take((size_t)Ln*Hn*Tn*4);
  float*          bqkv= (float*)take((size_t)Ln*3*Dn*4);
  float*          x   = (float*)take((size_t)Bn*Tn*Dn*4);
  unsigned short* hbuf= (unsigned short*)take((size_t)Bn*Tn*Dn*2);
  unsigned short* q   = (unsigned short*)take((size_t)Bn*Tn*Dn*2);   // q,k,v contiguous
  unsigned short* k   = (unsigned short*)take((size_t)Bn*Tn*Dn*2);
  unsigned short* v   = (unsigned short*)take((size_t)Bn*Tn*Dn*2);
  unsigned short* kp  = (unsigned short*)take((size_t)Bn*1920*HDn*2);
  unsigned short* vTp = (unsigned short*)take((size_t)Bn*1920*HDn*2);
  unsigned short* oT  = (unsigned short*)take((size_t)2*Bn*HDn*Tn*2);
  unsigned short* ao  = (unsigned short*)take((size_t)Bn*Tn*Dn*2);
  unsigned short* ff1 = (unsigned short*)take((size_t)Bn*Tn*Fn*2);
  if (off > ws_size) return;   // workspace insufficient: bail (output stays 0)
  // scores/attn alias the (temporally dead) ff1 buffer during attention.
  float*          scoresA = (float*)ff1;
  unsigned short* attnA   = (unsigned short*)(scoresA + (size_t)2*Bn*Tn*512);

  // ---- one-time-per-launch precompute ----
  transpose_w<<<dim3(Dn/32, Dn/32, Ln), 256, 0, stream>>>(Wq, WqT, Dn, Dn);
  transpose_w<<<dim3(Dn/32, Dn/32, Ln), 256, 0, stream>>>(Wk, WkT, Dn, Dn);
  transpose_w<<<dim3(Dn/32, Dn/32, Ln), 256, 0, stream>>>(Wv, WvT, Dn, Dn);
  transpose_w<<<dim3(Dn/32, Dn/32, Ln), 256, 0, stream>>>(Wo, WoT, Dn, Dn);
  transpose_w<<<dim3(Fn/32, Dn/32, Ln), 256, 0, stream>>>(W1, W1T, Dn, Fn);
  transpose_w<<<dim3(Dn/32, Fn/32, Ln), 256, 0, stream>>>(W2, W2T, Fn, Dn);
  pack_bias<<<(Ln*3*Dn)/256, 256, 0, stream>>>(bq, bk, bv, bqkv);
  ckern<<<Ln*Hn, 512, 0, stream>>>(gates, cbuf);
  gfill<<<(Ln*Hn*Tn*Tn)/256, 256, 0, stream>>>(cbuf, G);
  embed_kernel<<<Bn*Tn, 256, 0, stream>>>(tokens, embedp, pos, x);

  const int pref[8] = {0,512,1024,1280,1536,1664,1792,1856};
  const int MT = Bn*Tn;   // 8192

  for (int l=0; l<Ln; l++){
    // LN1 -> hbuf (bf16)
    ln_kernel<1><<<MT, 256, 0, stream>>>(x, ln1g + l*Dn, ln1b + l*Dn, hbuf);
    // QKV: one batched static-shape GEMM, z = {q,k,v}
    gemm_big<1, 8192, Dn, Dn, (long)Ln*Dn*Dn, (long)Bn*Tn*Dn, Dn>
        <<<dim3(Dn/128, MT/128, 3), 256, 0, stream>>>(
        hbuf, WqT + (size_t)l*Dn*Dn, q, bqkv + (size_t)l*3*Dn);
    // pool K,V
    pool_kernel<<<((long)Bn*1920*HDn + 255)/256, 256, 0, stream>>>(k, v, kp, vTp);

    for (int g=0; g<4; g++){
      int h0 = 2*g;
      int S  = Tn >> g;
      long koff = (long)Bn*HDn*pref[h0];
      // scores[zh,zb,t,s] = q_h . kp_h   (z = zh*16 + zb)
      gemm_kernel<0><<<dim3((S+127)/128, Tn/128, 32), 256, 0, stream>>>(
          q + h0*HDn, Dn, (long)Tn*Dn, (long)HDn,
          kp + koff, HDn, (long)S*HDn, (long)Bn*HDn*S,
          scoresA, S, (long)Tn*S, (long)Bn*Tn*S,
          nullptr, 0L, 4, 15,
          Tn, S, HDn);
      // softmax -> attn (bf16), 2*B*T rows
      switch (S){
        case 512: softmax_kernel<512><<<2*MT, 64, 0, stream>>>(scoresA, attnA); break;
        case 256: softmax_kernel<256><<<2*MT, 64, 0, stream>>>(scoresA, attnA); break;
        case 128: softmax_kernel<128><<<2*MT, 64, 0, stream>>>(scoresA, attnA); break;
        default:  softmax_kernel< 64><<<2*MT, 64, 0, stream>>>(scoresA, attnA); break;
      }
      // oT[zh,zb,d,t] = sum_s vTp[h,b,d,s] * attn[zh,zb,t,s]
      gemm_kernel<1><<<dim3(Tn/128, HDn/128, 32), 256, 0, stream>>>(
          vTp + koff, S, (long)HDn*S, (long)Bn*HDn*S,
          attnA, S, (long)Tn*S, (long)Bn*Tn*S,
          oT, Tn, (long)HDn*Tn, (long)Bn*HDn*Tn,
          nullptr, 0L, 4, 15,
          HDn, Tn, S);
      // spectral gating (circulant): ao[b,t,(h0+zh)*128+d] = sum_s G[t,s]*oT[zh,zb,d,s]
      gemm_kernel<1><<<dim3(HDn/128, Tn/128, 32), 256, 0, stream>>>(
          G + (size_t)(l*Hn + h0)*Tn*Tn, Tn, 0L, (long)Tn*Tn,
          oT, Tn, (long)HDn*Tn, (long)Bn*HDn*Tn,
          ao + h0*HDn, Dn, (long)Tn*Dn, (long)HDn,
          nullptr, 0L, 4, 15,
          Tn, HDn, Tn);
    }
    // Wo projection + residual into x (fp32)
    gemm_big<3, 8192, Dn, Dn, 0L, 0L, 0>
        <<<dim3(Dn/128, MT/128, 1), 256, 0, stream>>>(
        ao, WoT + (size_t)l*Dn*Dn, x, bo + l*Dn);
    // LN2 -> hbuf
    ln_kernel<1><<<MT, 256, 0, stream>>>(x, ln2g + l*Dn, ln2b + l*Dn, hbuf);
    // FFN1: GELU(h@W1+b1) -> ff1 (bf16)   [scores/attn alias is dead now]
    gemm_big<2, 8192, Fn, Dn, 0L, 0L, 0>
        <<<dim3(Fn/128, MT/128, 1), 256, 0, stream>>>(
        hbuf, W1T + (size_t)l*Dn*Fn, ff1, b1 + l*Fn);
    // FFN2 + residual into x
    gemm_big<3, 8192, Dn, Fn, 0L, 0L, 0>
        <<<dim3(Dn/128, MT/128, 1), 256, 0, stream>>>(
        ff1, W2T + (size_t)l*Dn*Fn, x, b2 + l*Dn);
  }
  // final LN -> d_out (fp32)
  ln_kernel<0><<<MT, 256, 0, stream>>>(x, lnfg, lnfb, out);
}

// Round 10
// 3377.507 us; speedup vs baseline: 1.0459x; 1.0459x over previous
//
#include <hip/hip_runtime.h>
#include <hip/hip_bf16.h>
#include <math.h>

#define Bn 16
#define Tn 512
#define Dn 1024
#define Hn 8
#define Ln 6
#define Fn 4096
#define HDn 128

typedef __attribute__((ext_vector_type(8))) short short8;
typedef __attribute__((ext_vector_type(4))) float f32x4;

__device__ __forceinline__ float bf2f(unsigned short u){
  union{float f; unsigned int i;} c; c.i = ((unsigned int)u)<<16; return c.f;
}
__device__ __forceinline__ unsigned short f2bf(float f){
  union{float f; unsigned int i;} c; c.f=f;
  unsigned int r = c.i + 0x7fffu + ((c.i>>16)&1u);
  return (unsigned short)(r>>16);
}

#define GLOAD(gp, lp) __builtin_amdgcn_global_load_lds( \
    (const __attribute__((address_space(1))) void*)(const void*)(gp), \
    (__attribute__((address_space(3))) void*)(void*)(lp), 16, 0, 0)

// ---------------- embedding: x[b,t,:] = embed[tok] + pos[t] ----------------
__global__ __launch_bounds__(256) void embed_kernel(
    const int* __restrict__ tok, const float* __restrict__ emb,
    const float* __restrict__ pos, float* __restrict__ x){
  long row = blockIdx.x;                 // b*T + t
  int t = (int)(row & (Tn-1));
  int tk = tok[row];
  int d = threadIdx.x*4;
  float4 e = *(const float4*)(emb + (long)tk*Dn + d);
  float4 p = *(const float4*)(pos + (long)t*Dn + d);
  float4 r; r.x=e.x+p.x; r.y=e.y+p.y; r.z=e.z+p.z; r.w=e.w+p.w;
  *(float4*)(x + row*(long)Dn + d) = r;
}

// ---------------- LayerNorm over D=1024 (one block per row) ----------------
template<int OUTBF>
__global__ __launch_bounds__(256) void ln_kernel(
    const float* __restrict__ x, const float* __restrict__ g,
    const float* __restrict__ b, void* __restrict__ outp){
  long row = blockIdx.x;
  const float* xr = x + row*(long)Dn;
  int tid = threadIdx.x;
  float4 v4 = *(const float4*)(xr + tid*4);
  float s  = v4.x+v4.y+v4.z+v4.w;
  float s2 = v4.x*v4.x + v4.y*v4.y + v4.z*v4.z + v4.w*v4.w;
  #pragma unroll
  for (int o=32;o;o>>=1){ s += __shfl_xor(s,o); s2 += __shfl_xor(s2,o); }
  __shared__ float rs[4], rs2[4];
  int w = tid>>6;
  if ((tid&63)==0){ rs[w]=s; rs2[w]=s2; }
  __syncthreads();
  s  = rs[0]+rs[1]+rs[2]+rs[3];
  s2 = rs2[0]+rs2[1]+rs2[2]+rs2[3];
  float mu  = s*(1.f/Dn);
  float var = s2*(1.f/Dn) - mu*mu;
  float rstd = rsqrtf(var + 1e-5f);
  float4 gg = *(const float4*)(g + tid*4);
  float4 bb = *(const float4*)(b + tid*4);
  float o0 = (v4.x-mu)*rstd*gg.x + bb.x;
  float o1 = (v4.y-mu)*rstd*gg.y + bb.y;
  float o2 = (v4.z-mu)*rstd*gg.z + bb.z;
  float o3 = (v4.w-mu)*rstd*gg.w + bb.w;
  if (OUTBF){
    unsigned short* o = (unsigned short*)outp + row*(long)Dn + tid*4;
    o[0]=f2bf(o0); o[1]=f2bf(o1); o[2]=f2bf(o2); o[3]=f2bf(o3);
  } else {
    float* o = (float*)outp + row*(long)Dn + tid*4;
    o[0]=o0; o[1]=o1; o[2]=o2; o[3]=o3;
  }
}

// ------------- weight transpose+convert: W[K][N] f32 -> WT[N][K] bf16 -------
__global__ __launch_bounds__(256) void transpose_w(
    const float* __restrict__ W, unsigned short* __restrict__ WT, int Kd, int Nd){
  __shared__ float tile[32][33];
  long lofs = (long)blockIdx.z * Kd * Nd;
  int n0 = blockIdx.x*32, k0 = blockIdx.y*32;
  int tx = threadIdx.x & 31, ty = threadIdx.x >> 5;   // ty 0..7
  #pragma unroll
  for (int i=0;i<4;i++){
    int kk = k0 + ty + i*8;
    tile[ty+i*8][tx] = W[lofs + (long)kk*Nd + n0 + tx];
  }
  __syncthreads();
  #pragma unroll
  for (int i=0;i<4;i++){
    int nn = n0 + ty + i*8;
    WT[lofs + (long)nn*Kd + k0 + tx] = f2bf(tile[tx][ty+i*8]);
  }
}

// ---- pack QKV biases into bqkv[L][3][D] for the batched QKV GEMM ----------
__global__ __launch_bounds__(256) void pack_bias(
    const float* __restrict__ bq, const float* __restrict__ bk,
    const float* __restrict__ bv, float* __restrict__ bqkv){
  int i = blockIdx.x*256 + threadIdx.x;   // l*3*Dn + w*Dn + d
  int l = i / (3*Dn); int r = i - l*3*Dn; int w = r / Dn; int d = r - w*Dn;
  const float* src = (w==0)? bq : ((w==1)? bk : bv);
  bqkv[i] = src[l*Dn + d];
}

// ------- circulant kernel c = irfft(gate per rfft-bin), per (layer,head) ----
__global__ __launch_bounds__(512) void ckern(
    const float* __restrict__ gates, float* __restrict__ cbuf){
  int lh = blockIdx.x;                   // l*H + h
  __shared__ float gb[16];
  if (threadIdx.x < 16) gb[threadIdx.x] = gates[lh*16 + threadIdx.x];
  __syncthreads();
  int m = threadIdx.x;                   // 0..511
  float acc = gb[0];                     // bin 0, weight 1, band 0
  for (int j=1;j<256;j++){
    int band = (j*16)/257;               // (j*BANDS)//nb
    int kmod = (j*m) & 511;              // exact phase reduction
    acc += 2.f*gb[band]*cosf(1.2271846303085129e-2f * (float)kmod); // 2pi/512
  }
  acc += gb[15] * ((m & 1) ? -1.f : 1.f);   // Nyquist bin, band 15
  cbuf[lh*512 + m] = acc * (1.f/512.f);
}

// --------- materialize G[l,h,t,s] = c[(t-s) mod 512] as bf16 ---------------
__global__ __launch_bounds__(256) void gfill(
    const float* __restrict__ cbuf, unsigned short* __restrict__ G){
  long idx = (long)blockIdx.x*256 + threadIdx.x;   // grid sized exactly
  int lh = (int)(idx >> 18);
  int rem = (int)(idx & 262143);
  int t = rem >> 9, s = rem & 511;
  G[idx] = f2bf(cbuf[lh*512 + ((t - s) & 511)]);
}

// --------- pool K,V per head: kp[b,s,d] mean, vTp[b,d,s] mean ---------------
__global__ __launch_bounds__(256) void pool_kernel(
    const unsigned short* __restrict__ kin, const unsigned short* __restrict__ vin,
    unsigned short* __restrict__ kp, unsigned short* __restrict__ vTp){
  long idx = (long)blockIdx.x*256 + threadIdx.x;
  if (idx >= (long)Bn*1920*HDn) return;
  long rem = idx; int hh = 0; int S = 512;
  for (hh=0; hh<8; hh++){
    S = 512 >> (hh>>1);
    long seg = (long)Bn*S*HDn;
    if (rem < seg) break;
    rem -= seg;
  }
  int r = 512 / S;
  int d = (int)(rem % HDn);
  long t2 = rem / HDn;
  int s = (int)(t2 % S);
  int b = (int)(t2 / S);
  const unsigned short* kb = kin + ((long)(b*Tn + s*r))*Dn + hh*HDn + d;
  const unsigned short* vb = vin + ((long)(b*Tn + s*r))*Dn + hh*HDn + d;
  float ks=0.f, vs=0.f;
  for (int j=0;j<r;j++){ ks += bf2f(kb[(long)j*Dn]); vs += bf2f(vb[(long)j*Dn]); }
  float inv = 1.f/(float)r;
  int pref=0;
  for (int g2=0; g2<hh; g2++) pref += 512 >> (g2>>1);
  long segb = (long)Bn*HDn*pref;
  kp [segb + ((long)b*S + s)*HDn + d] = f2bf(ks*inv);
  vTp[segb + ((long)b*HDn + d)*S + s] = f2bf(vs*inv);
}

// --------- row softmax (scale 1/sqrt(128)), fp32 in -> bf16 out -------------
template<int S>
__global__ __launch_bounds__(64) void softmax_kernel(
    const float* __restrict__ sc, unsigned short* __restrict__ at){
  const int NV = S/64;
  long row = blockIdx.x;
  const float* r = sc + row*(long)S;
  int lane = threadIdx.x;
  float vals[NV];
  float mx = -1e30f;
  #pragma unroll
  for (int i=0;i<NV;i++){ vals[i] = r[lane + i*64] * 0.08838834764831845f; mx = fmaxf(mx, vals[i]); }
  #pragma unroll
  for (int o=32;o;o>>=1) mx = fmaxf(mx, __shfl_xor(mx, o));
  float sum = 0.f;
  #pragma unroll
  for (int i=0;i<NV;i++){ vals[i] = expf(vals[i]-mx); sum += vals[i]; }
  #pragma unroll
  for (int o=32;o;o>>=1) sum += __shfl_xor(sum, o);
  float inv = 1.f/sum;
  #pragma unroll
  for (int i=0;i<NV;i++) at[row*(long)S + lane + i*64] = f2bf(vals[i]*inv);
}

// ----------------- generic batched bf16 MFMA GEMM (attention path) ----------
// r7-proven schedule: stage(t+1); vmcnt(8) (waits tile-t loads, leaves the 8
// just-issued in flight -> a full compute phase of latency cover); barrier;
// compute; barrier.  No setprio (m190: negative on lockstep GEMM).
template<int MODE>
__global__ __launch_bounds__(256)
void gemm_kernel(const unsigned short* __restrict__ A, int lda, long sAb, long sAh,
                 const unsigned short* __restrict__ Bt, int ldb, long sBb, long sBh,
                 void* __restrict__ Cout, int ldc, long sCb, long sCh,
                 const float* __restrict__ bias, long sbias,
                 int zshift, int zmask,
                 int M, int N, int K)
{
  __shared__ unsigned short AB[2][2][128*64];
  int z = blockIdx.z;
  int zb = z & zmask, zh = z >> zshift;
  const unsigned short* Az = A + (long)zb*sAb + (long)zh*sAh;
  const unsigned short* Bz = Bt + (long)zb*sBb + (long)zh*sBh;
  const float* biasz = bias ? (bias + (long)zh*sbias) : nullptr;
  int m0 = blockIdx.y*128, n0 = blockIdx.x*128;
  int tid = threadIdx.x;
  int lane = tid & 63, wid = tid >> 6;
  int wm = wid >> 1, wn = wid & 1;
  f32x4 zero4 = {0.f,0.f,0.f,0.f};
  f32x4 acc[4][4];
  #pragma unroll
  for (int m=0;m<4;m++)
    #pragma unroll
    for (int n=0;n<4;n++)
      acc[m][n] = zero4;
  const int r16 = lane & 15, kq = lane >> 4;

  auto stage = [&](int buf, int k0){
    #pragma unroll
    for (int i=0;i<4;i++){
      int chunk = i*256 + tid;                 // 1024 chunks of 16B
      int row = chunk >> 3, c = chunk & 7;
      int cg = (c ^ (row & 7)) * 8;            // pre-swizzled global col (elems)
      int gm = m0 + row; gm = gm < M ? gm : M-1;
      GLOAD(Az + (long)gm*lda + k0 + cg, AB[buf][0] + (i*256 + wid*64)*8);
    }
    #pragma unroll
    for (int i=0;i<4;i++){
      int chunk = i*256 + tid;
      int row = chunk >> 3, c = chunk & 7;
      int cg = (c ^ (row & 7)) * 8;
      int gn = n0 + row; gn = gn < N ? gn : N-1;
      GLOAD(Bz + (long)gn*ldb + k0 + cg, AB[buf][1] + (i*256 + wid*64)*8);
    }
  };

  int NT = K >> 6;
  stage(0, 0);
  for (int t = 0; t < NT; t++){
    if (t + 1 < NT){
      stage((t+1)&1, (t+1)*64);
      asm volatile("s_waitcnt vmcnt(8)" ::: "memory");
    } else {
      asm volatile("s_waitcnt vmcnt(0)" ::: "memory");
    }
    __builtin_amdgcn_s_barrier();
    const unsigned short* As = AB[t&1][0];
    const unsigned short* Bs = AB[t&1][1];
    #pragma unroll
    for (int kk=0; kk<64; kk+=32){
      short8 af[4], bfr[4];
      int kb = (kk + kq*8) * 2;
      #pragma unroll
      for (int m=0;m<4;m++){
        int row = wm*64 + m*16 + r16;
        af[m] = *(const short8*)((const char*)As + row*128 + (kb ^ ((row & 7) << 4)));
      }
      #pragma unroll
      for (int n=0;n<4;n++){
        int row = wn*64 + n*16 + r16;
        bfr[n] = *(const short8*)((const char*)Bs + row*128 + (kb ^ ((row & 7) << 4)));
      }
      #pragma unroll
      for (int m=0;m<4;m++)
        #pragma unroll
        for (int n=0;n<4;n++)
          acc[m][n] = __builtin_amdgcn_mfma_f32_16x16x32_bf16(af[m], bfr[n], acc[m][n], 0, 0, 0);
    }
    __builtin_amdgcn_s_barrier();
  }
  #pragma unroll
  for (int n=0;n<4;n++){
    int col = n0 + wn*64 + n*16 + r16;
    if (col >= N) continue;
    float bvv = 0.f;
    if (MODE != 0 && biasz != nullptr) bvv = biasz[col];
    #pragma unroll
    for (int m=0;m<4;m++){
      #pragma unroll
      for (int e=0;e<4;e++){
        int row = m0 + wm*64 + m*16 + kq*4 + e;
        if (row >= M) continue;
        float vv = acc[m][n][e] + bvv;
        long cidx = (long)zb*sCb + (long)zh*sCh + (long)row*ldc + col;
        if (MODE == 0)      ((float*)Cout)[cidx] = vv;
        else                ((unsigned short*)Cout)[cidx] = f2bf(vv);
      }
    }
  }
}

// ----------------- static-shape 128-tile GEMM (all dense projections) -------
// r7-proven schedule (see gemm_kernel), natural block order (no XCD remap —
// r7 showed it triples L2 fetch here), no setprio.
// MODE 1: +bias -> bf16 | 2: +bias,GELU -> bf16 | 3: +bias, += into fp32 C
template<int MODE, int Mt, int Nt, int Kt, long SBH, long SCH, int BIASST>
__global__ __launch_bounds__(256)
void gemm_big(const unsigned short* __restrict__ A,
              const unsigned short* __restrict__ Bt,
              void* __restrict__ Cout,
              const float* __restrict__ bias)
{
  __shared__ char shraw[2][32768];              // dbuf: As 16KB + Bs 16KB each
  int zh = blockIdx.z;
  const unsigned short* Bz = Bt + (long)zh*SBH;
  const float* biasz = bias + (long)zh*BIASST;
  int m0 = blockIdx.y*128, n0 = blockIdx.x*128;
  int tid = threadIdx.x;
  int lane = tid & 63, wid = tid >> 6;
  int wm = wid >> 1, wn = wid & 1;
  f32x4 zero4 = {0.f,0.f,0.f,0.f};
  f32x4 acc[4][4];
  #pragma unroll
  for (int m=0;m<4;m++)
    #pragma unroll
    for (int n=0;n<4;n++)
      acc[m][n] = zero4;
  const int r16 = lane & 15, kq = lane >> 4;

  const unsigned short* pA[4];
  const unsigned short* pB[4];
  #pragma unroll
  for (int i=0;i<4;i++){
    int chunk = i*256 + tid;
    int row = chunk >> 3, c = chunk & 7;
    int cg = (c ^ (row & 7)) * 8;
    pA[i] = A  + (long)(m0 + row)*Kt + cg;
    pB[i] = Bz + (long)(n0 + row)*Kt + cg;
  }
  auto stage = [&](int buf, int k0){
    unsigned short* As = (unsigned short*)shraw[buf];
    #pragma unroll
    for (int i=0;i<4;i++) GLOAD(pA[i] + k0, As + (i*256 + wid*64)*8);
    #pragma unroll
    for (int i=0;i<4;i++) GLOAD(pB[i] + k0, As + 8192 + (i*256 + wid*64)*8);
  };

  constexpr int NT = Kt/64;
  stage(0, 0);
  for (int t = 0; t < NT; t++){
    if (t + 1 < NT){
      stage((t+1)&1, (t+1)*64);
      asm volatile("s_waitcnt vmcnt(8)" ::: "memory");
    } else {
      asm volatile("s_waitcnt vmcnt(0)" ::: "memory");
    }
    __builtin_amdgcn_s_barrier();
    const unsigned short* As = (const unsigned short*)shraw[t&1];
    const unsigned short* Bs = As + 8192;
    #pragma unroll
    for (int kk=0; kk<64; kk+=32){
      short8 af[4], bfr[4];
      int kb = (kk + kq*8) * 2;
      #pragma unroll
      for (int m=0;m<4;m++){
        int row = wm*64 + m*16 + r16;
        af[m] = *(const short8*)((const char*)As + row*128 + (kb ^ ((row & 7) << 4)));
      }
      #pragma unroll
      for (int n=0;n<4;n++){
        int row = wn*64 + n*16 + r16;
        bfr[n] = *(const short8*)((const char*)Bs + row*128 + (kb ^ ((row & 7) << 4)));
      }
      #pragma unroll
      for (int m=0;m<4;m++)
        #pragma unroll
        for (int n=0;n<4;n++)
          acc[m][n] = __builtin_amdgcn_mfma_f32_16x16x32_bf16(af[m], bfr[n], acc[m][n], 0, 0, 0);
    }
    __builtin_amdgcn_s_barrier();
  }

  if (MODE == 1 || MODE == 2){
    // bf16 tile via LDS (stride 136 shorts = 272B = 17*16B, rows 16B-aligned)
    unsigned short* shb = (unsigned short*)&shraw[0][0];
    #pragma unroll
    for (int n=0;n<4;n++){
      int col = wn*64 + n*16 + r16;
      float bvv = biasz[n0 + col];
      #pragma unroll
      for (int m=0;m<4;m++){
        #pragma unroll
        for (int e=0;e<4;e++){
          int row = wm*64 + m*16 + kq*4 + e;
          float vv = acc[m][n][e] + bvv;
          if (MODE == 2) vv = 0.5f*vv*(1.f + erff(vv*0.7071067811865475f));
          shb[row*136 + col] = f2bf(vv);
        }
      }
    }
    __syncthreads();
    // FULL 128x128 tile = 2048 chunks of 8 shorts
    #pragma unroll
    for (int i=0;i<8;i++){
      int chunk = i*256 + tid;
      int row = chunk >> 4, col = (chunk & 15)*8;
      short8 vv8 = *(const short8*)(shb + row*136 + col);
      *(short8*)((unsigned short*)Cout + (long)zh*SCH +
                 (long)(m0 + row)*Nt + n0 + col) = vv8;
    }
  } else {
    // MODE 3: fp32 accumulate, two 64-row phases through LDS (stride 136 floats)
    float* shf = (float*)&shraw[0][0];
    #pragma unroll
    for (int ph=0; ph<2; ph++){
      __syncthreads();
      if (wm == ph){
        #pragma unroll
        for (int n=0;n<4;n++){
          int col = wn*64 + n*16 + r16;
          float bvv = biasz[n0 + col];
          #pragma unroll
          for (int m=0;m<4;m++){
            #pragma unroll
            for (int e=0;e<4;e++){
              int rl = m*16 + kq*4 + e;
              shf[rl*136 + col] = acc[m][n][e] + bvv;
            }
          }
        }
      }
      __syncthreads();
      #pragma unroll
      for (int i=0;i<8;i++){
        int chunk = i*256 + tid;                // 2048 chunks of 4 floats
        int row = chunk >> 5, col = (chunk & 31)*4;
        float4 vv = *(const float4*)(shf + row*136 + col);
        float* cp = (float*)Cout + (long)(m0 + ph*64 + row)*Nt + n0 + col;
        float4 o = *(const float4*)cp;
        o.x += vv.x; o.y += vv.y; o.z += vv.z; o.w += vv.w;
        *(float4*)cp = o;
      }
    }
  }
}

// ---------------------------------------------------------------------------
extern "C" void kernel_launch(void* const* d_in, const int* in_sizes, int n_in,
                              void* d_out, int out_size, void* d_ws, size_t ws_size,
                              hipStream_t stream){
  const int*   tokens = (const int*)  d_in[0];
  const float* embedp = (const float*)d_in[1];
  const float* pos    = (const float*)d_in[2];
  const float* Wq  = (const float*)d_in[3];
  const float* bq  = (const float*)d_in[4];
  const float* Wk  = (const float*)d_in[5];
  const float* bk  = (const float*)d_in[6];
  const float* Wv  = (const float*)d_in[7];
  const float* bv  = (const float*)d_in[8];
  const float* Wo  = (const float*)d_in[9];
  const float* bo  = (const float*)d_in[10];
  const float* ln1g= (const float*)d_in[11];
  const float* ln1b= (const float*)d_in[12];
  const float* ln2g= (const float*)d_in[13];
  const float* ln2b= (const float*)d_in[14];
  const float* W1  = (const float*)d_in[15];
  const float* b1  = (const float*)d_in[16];
  const float* W2  = (const float*)d_in[17];
  const float* b2  = (const float*)d_in[18];
  const float* gates=(const float*)d_in[19];
  const float* lnfg= (const float*)d_in[20];
  const float* lnfb= (const float*)d_in[21];
  float* out = (float*)d_out;

  char* base = (char*)d_ws;
  size_t off = 0;
  auto take = [&](size_t bytes)->char*{
    char* p = base + off;
    off = (off + bytes + 255) & ~(size_t)255;
    return p;
  };
  unsigned short* WqT = (unsigned short*)take((size_t)Ln*Dn*Dn*2);
  unsigned short* WkT = (unsigned short*)take((size_t)Ln*Dn*Dn*2);   // contiguous after WqT
  unsigned short* WvT = (unsigned short*)take((size_t)Ln*Dn*Dn*2);   // contiguous after WkT
  unsigned short* WoT = (unsigned short*)take((size_t)Ln*Dn*Dn*2);
  unsigned short* W1T = (unsigned short*)take((size_t)Ln*Dn*Fn*2);
  unsigned short* W2T = (unsigned short*)take((size_t)Ln*Dn*Fn*2);
  unsigned short* G   = (unsigned short*)take((size_t)Ln*Hn*Tn*Tn*2);
  float*          cbuf= (float*)take((size_t)Ln*Hn*Tn*4);
  float*          bqkv= (float*)take((size_t)Ln*3*Dn*4);
  float*          x   = (float*)take((size_t)Bn*Tn*Dn*4);
  unsigned short* hbuf= (unsigned short*)take((size_t)Bn*Tn*Dn*2);
  unsigned short* q   = (unsigned short*)take((size_t)Bn*Tn*Dn*2);   // q,k,v contiguous
  unsigned short* k   = (unsigned short*)take((size_t)Bn*Tn*Dn*2);
  unsigned short* v   = (unsigned short*)take((size_t)Bn*Tn*Dn*2);
  unsigned short* kp  = (unsigned short*)take((size_t)Bn*1920*HDn*2);
  unsigned short* vTp = (unsigned short*)take((size_t)Bn*1920*HDn*2);
  unsigned short* oT  = (unsigned short*)take((size_t)2*Bn*HDn*Tn*2);
  unsigned short* ao  = (unsigned short*)take((size_t)Bn*Tn*Dn*2);
  unsigned short* ff1 = (unsigned short*)take((size_t)Bn*Tn*Fn*2);
  if (off > ws_size) return;   // workspace insufficient: bail (output stays 0)
  // scores/attn alias the (temporally dead) ff1 buffer during attention.
  float*          scoresA = (float*)ff1;
  unsigned short* attnA   = (unsigned short*)(scoresA + (size_t)2*Bn*Tn*512);

  // ---- one-time-per-launch precompute ----
  transpose_w<<<dim3(Dn/32, Dn/32, Ln), 256, 0, stream>>>(Wq, WqT, Dn, Dn);
  transpose_w<<<dim3(Dn/32, Dn/32, Ln), 256, 0, stream>>>(Wk, WkT, Dn, Dn);
  transpose_w<<<dim3(Dn/32, Dn/32, Ln), 256, 0, stream>>>(Wv, WvT, Dn, Dn);
  transpose_w<<<dim3(Dn/32, Dn/32, Ln), 256, 0, stream>>>(Wo, WoT, Dn, Dn);
  transpose_w<<<dim3(Fn/32, Dn/32, Ln), 256, 0, stream>>>(W1, W1T, Dn, Fn);
  transpose_w<<<dim3(Dn/32, Fn/32, Ln), 256, 0, stream>>>(W2, W2T, Fn, Dn);
  pack_bias<<<(Ln*3*Dn)/256, 256, 0, stream>>>(bq, bk, bv, bqkv);
  ckern<<<Ln*Hn, 512, 0, stream>>>(gates, cbuf);
  gfill<<<(Ln*Hn*Tn*Tn)/256, 256, 0, stream>>>(cbuf, G);
  embed_kernel<<<Bn*Tn, 256, 0, stream>>>(tokens, embedp, pos, x);

  const int pref[8] = {0,512,1024,1280,1536,1664,1792,1856};
  const int MT = Bn*Tn;   // 8192

  for (int l=0; l<Ln; l++){
    // LN1 -> hbuf (bf16)
    ln_kernel<1><<<MT, 256, 0, stream>>>(x, ln1g + l*Dn, ln1b + l*Dn, hbuf);
    // QKV: one batched static-shape GEMM, z = {q,k,v}
    gemm_big<1, 8192, Dn, Dn, (long)Ln*Dn*Dn, (long)Bn*Tn*Dn, Dn>
        <<<dim3(Dn/128, MT/128, 3), 256, 0, stream>>>(
        hbuf, WqT + (size_t)l*Dn*Dn, q, bqkv + (size_t)l*3*Dn);
    // pool K,V
    pool_kernel<<<((long)Bn*1920*HDn + 255)/256, 256, 0, stream>>>(k, v, kp, vTp);

    for (int g=0; g<4; g++){
      int h0 = 2*g;
      int S  = Tn >> g;
      long koff = (long)Bn*HDn*pref[h0];
      // scores[zh,zb,t,s] = q_h . kp_h   (z = zh*16 + zb)
      gemm_kernel<0><<<dim3((S+127)/128, Tn/128, 32), 256, 0, stream>>>(
          q + h0*HDn, Dn, (long)Tn*Dn, (long)HDn,
          kp + koff, HDn, (long)S*HDn, (long)Bn*HDn*S,
          scoresA, S, (long)Tn*S, (long)Bn*Tn*S,
          nullptr, 0L, 4, 15,
          Tn, S, HDn);
      // softmax -> attn (bf16), 2*B*T rows
      switch (S){
        case 512: softmax_kernel<512><<<2*MT, 64, 0, stream>>>(scoresA, attnA); break;
        case 256: softmax_kernel<256><<<2*MT, 64, 0, stream>>>(scoresA, attnA); break;
        case 128: softmax_kernel<128><<<2*MT, 64, 0, stream>>>(scoresA, attnA); break;
        default:  softmax_kernel< 64><<<2*MT, 64, 0, stream>>>(scoresA, attnA); break;
      }
      // oT[zh,zb,d,t] = sum_s vTp[h,b,d,s] * attn[zh,zb,t,s]
      gemm_kernel<1><<<dim3(Tn/128, HDn/128, 32), 256, 0, stream>>>(
          vTp + koff, S, (long)HDn*S, (long)Bn*HDn*S,
          attnA, S, (long)Tn*S, (long)Bn*Tn*S,
          oT, Tn, (long)HDn*Tn, (long)Bn*HDn*Tn,
          nullptr, 0L, 4, 15,
          HDn, Tn, S);
      // spectral gating (circulant): ao[b,t,(h0+zh)*128+d] = sum_s G[t,s]*oT[zh,zb,d,s]
      gemm_kernel<1><<<dim3(HDn/128, Tn/128, 32), 256, 0, stream>>>(
          G + (size_t)(l*Hn + h0)*Tn*Tn, Tn, 0L, (long)Tn*Tn,
          oT, Tn, (long)HDn*Tn, (long)Bn*HDn*Tn,
          ao + h0*HDn, Dn, (long)Tn*Dn, (long)HDn,
          nullptr, 0L, 4, 15,
          Tn, HDn, Tn);
    }
    // Wo projection + residual into x (fp32)
    gemm_big<3, 8192, Dn, Dn, 0L, 0L, 0>
        <<<dim3(Dn/128, MT/128, 1), 256, 0, stream>>>(
        ao, WoT + (size_t)l*Dn*Dn, x, bo + l*Dn);
    // LN2 -> hbuf
    ln_kernel<1><<<MT, 256, 0, stream>>>(x, ln2g + l*Dn, ln2b + l*Dn, hbuf);
    // FFN1: GELU(h@W1+b1) -> ff1 (bf16)   [scores/attn alias is dead now]
    gemm_big<2, 8192, Fn, Dn, 0L, 0L, 0>
        <<<dim3(Fn/128, MT/128, 1), 256, 0, stream>>>(
        hbuf, W1T + (size_t)l*Dn*Fn, ff1, b1 + l*Fn);
    // FFN2 + residual into x
    gemm_big<3, 8192, Dn, Fn, 0L, 0L, 0>
        <<<dim3(Dn/128, MT/128, 1), 256, 0, stream>>>(
        ff1, W2T + (size_t)l*Dn*Fn, x, b2 + l*Dn);
  }
  // final LN -> d_out (fp32)
  ln_kernel<0><<<MT, 256, 0, stream>>>(x, lnfg, lnfb, out);
}

// Round 11
// 3220.277 us; speedup vs baseline: 1.0970x; 1.0488x over previous
//
#include <hip/hip_runtime.h>
#include <hip/hip_bf16.h>
#include <math.h>

#define Bn 16
#define Tn 512
#define Dn 1024
#define Hn 8
#define Ln 6
#define Fn 4096
#define HDn 128

typedef __attribute__((ext_vector_type(8))) short short8;
typedef __attribute__((ext_vector_type(4))) float f32x4;

__device__ __forceinline__ float bf2f(unsigned short u){
  union{float f; unsigned int i;} c; c.i = ((unsigned int)u)<<16; return c.f;
}
__device__ __forceinline__ unsigned short f2bf(float f){
  union{float f; unsigned int i;} c; c.f=f;
  unsigned int r = c.i + 0x7fffu + ((c.i>>16)&1u);
  return (unsigned short)(r>>16);
}

#define GLOAD(gp, lp) __builtin_amdgcn_global_load_lds( \
    (const __attribute__((address_space(1))) void*)(const void*)(gp), \
    (__attribute__((address_space(3))) void*)(void*)(lp), 16, 0, 0)

// ---------------- embedding: x[b,t,:] = embed[tok] + pos[t] ----------------
__global__ __launch_bounds__(256) void embed_kernel(
    const int* __restrict__ tok, const float* __restrict__ emb,
    const float* __restrict__ pos, float* __restrict__ x){
  long row = blockIdx.x;                 // b*T + t
  int t = (int)(row & (Tn-1));
  int tk = tok[row];
  int d = threadIdx.x*4;
  float4 e = *(const float4*)(emb + (long)tk*Dn + d);
  float4 p = *(const float4*)(pos + (long)t*Dn + d);
  float4 r; r.x=e.x+p.x; r.y=e.y+p.y; r.z=e.z+p.z; r.w=e.w+p.w;
  *(float4*)(x + row*(long)Dn + d) = r;
}

// ---------------- LayerNorm over D=1024 (one block per row) ----------------
template<int OUTBF>
__global__ __launch_bounds__(256) void ln_kernel(
    const float* __restrict__ x, const float* __restrict__ g,
    const float* __restrict__ b, void* __restrict__ outp){
  long row = blockIdx.x;
  const float* xr = x + row*(long)Dn;
  int tid = threadIdx.x;
  float4 v4 = *(const float4*)(xr + tid*4);
  float s  = v4.x+v4.y+v4.z+v4.w;
  float s2 = v4.x*v4.x + v4.y*v4.y + v4.z*v4.z + v4.w*v4.w;
  #pragma unroll
  for (int o=32;o;o>>=1){ s += __shfl_xor(s,o); s2 += __shfl_xor(s2,o); }
  __shared__ float rs[4], rs2[4];
  int w = tid>>6;
  if ((tid&63)==0){ rs[w]=s; rs2[w]=s2; }
  __syncthreads();
  s  = rs[0]+rs[1]+rs[2]+rs[3];
  s2 = rs2[0]+rs2[1]+rs2[2]+rs2[3];
  float mu  = s*(1.f/Dn);
  float var = s2*(1.f/Dn) - mu*mu;
  float rstd = rsqrtf(var + 1e-5f);
  float4 gg = *(const float4*)(g + tid*4);
  float4 bb = *(const float4*)(b + tid*4);
  float o0 = (v4.x-mu)*rstd*gg.x + bb.x;
  float o1 = (v4.y-mu)*rstd*gg.y + bb.y;
  float o2 = (v4.z-mu)*rstd*gg.z + bb.z;
  float o3 = (v4.w-mu)*rstd*gg.w + bb.w;
  if (OUTBF){
    unsigned short* o = (unsigned short*)outp + row*(long)Dn + tid*4;
    o[0]=f2bf(o0); o[1]=f2bf(o1); o[2]=f2bf(o2); o[3]=f2bf(o3);
  } else {
    float* o = (float*)outp + row*(long)Dn + tid*4;
    o[0]=o0; o[1]=o1; o[2]=o2; o[3]=o3;
  }
}

// ------------- weight transpose+convert: W[K][N] f32 -> WT[N][K] bf16 -------
__global__ __launch_bounds__(256) void transpose_w(
    const float* __restrict__ W, unsigned short* __restrict__ WT, int Kd, int Nd){
  __shared__ float tile[32][33];
  long lofs = (long)blockIdx.z * Kd * Nd;
  int n0 = blockIdx.x*32, k0 = blockIdx.y*32;
  int tx = threadIdx.x & 31, ty = threadIdx.x >> 5;   // ty 0..7
  #pragma unroll
  for (int i=0;i<4;i++){
    int kk = k0 + ty + i*8;
    tile[ty+i*8][tx] = W[lofs + (long)kk*Nd + n0 + tx];
  }
  __syncthreads();
  #pragma unroll
  for (int i=0;i<4;i++){
    int nn = n0 + ty + i*8;
    WT[lofs + (long)nn*Kd + k0 + tx] = f2bf(tile[tx][ty+i*8]);
  }
}

// ---- pack QKV biases into bqkv[L][3][D] for the batched QKV GEMM ----------
__global__ __launch_bounds__(256) void pack_bias(
    const float* __restrict__ bq, const float* __restrict__ bk,
    const float* __restrict__ bv, float* __restrict__ bqkv){
  int i = blockIdx.x*256 + threadIdx.x;   // l*3*Dn + w*Dn + d
  int l = i / (3*Dn); int r = i - l*3*Dn; int w = r / Dn; int d = r - w*Dn;
  const float* src = (w==0)? bq : ((w==1)? bk : bv);
  bqkv[i] = src[l*Dn + d];
}

// ------- circulant kernel c = irfft(gate per rfft-bin), per (layer,head) ----
__global__ __launch_bounds__(512) void ckern(
    const float* __restrict__ gates, float* __restrict__ cbuf){
  int lh = blockIdx.x;                   // l*H + h
  __shared__ float gb[16];
  if (threadIdx.x < 16) gb[threadIdx.x] = gates[lh*16 + threadIdx.x];
  __syncthreads();
  int m = threadIdx.x;                   // 0..511
  float acc = gb[0];                     // bin 0, weight 1, band 0
  for (int j=1;j<256;j++){
    int band = (j*16)/257;               // (j*BANDS)//nb
    int kmod = (j*m) & 511;              // exact phase reduction
    acc += 2.f*gb[band]*cosf(1.2271846303085129e-2f * (float)kmod); // 2pi/512
  }
  acc += gb[15] * ((m & 1) ? -1.f : 1.f);   // Nyquist bin, band 15
  cbuf[lh*512 + m] = acc * (1.f/512.f);
}

// --------- materialize G[l,h,t,s] = c[(t-s) mod 512] as bf16 ---------------
__global__ __launch_bounds__(256) void gfill(
    const float* __restrict__ cbuf, unsigned short* __restrict__ G){
  long idx = (long)blockIdx.x*256 + threadIdx.x;   // grid sized exactly
  int lh = (int)(idx >> 18);
  int rem = (int)(idx & 262143);
  int t = rem >> 9, s = rem & 511;
  G[idx] = f2bf(cbuf[lh*512 + ((t - s) & 511)]);
}

// --------- pool K,V per head: kp[b,s,d] mean, vTp[b,d,s] mean ---------------
__global__ __launch_bounds__(256) void pool_kernel(
    const unsigned short* __restrict__ kin, const unsigned short* __restrict__ vin,
    unsigned short* __restrict__ kp, unsigned short* __restrict__ vTp){
  long idx = (long)blockIdx.x*256 + threadIdx.x;
  if (idx >= (long)Bn*1920*HDn) return;
  long rem = idx; int hh = 0; int S = 512;
  for (hh=0; hh<8; hh++){
    S = 512 >> (hh>>1);
    long seg = (long)Bn*S*HDn;
    if (rem < seg) break;
    rem -= seg;
  }
  int r = 512 / S;
  int d = (int)(rem % HDn);
  long t2 = rem / HDn;
  int s = (int)(t2 % S);
  int b = (int)(t2 / S);
  const unsigned short* kb = kin + ((long)(b*Tn + s*r))*Dn + hh*HDn + d;
  const unsigned short* vb = vin + ((long)(b*Tn + s*r))*Dn + hh*HDn + d;
  float ks=0.f, vs=0.f;
  for (int j=0;j<r;j++){ ks += bf2f(kb[(long)j*Dn]); vs += bf2f(vb[(long)j*Dn]); }
  float inv = 1.f/(float)r;
  int pref=0;
  for (int g2=0; g2<hh; g2++) pref += 512 >> (g2>>1);
  long segb = (long)Bn*HDn*pref;
  kp [segb + ((long)b*S + s)*HDn + d] = f2bf(ks*inv);
  vTp[segb + ((long)b*HDn + d)*S + s] = f2bf(vs*inv);
}

// --------- row softmax (scale 1/sqrt(128)), fp32 in -> bf16 out -------------
template<int S>
__global__ __launch_bounds__(64) void softmax_kernel(
    const float* __restrict__ sc, unsigned short* __restrict__ at){
  const int NV = S/64;
  long row = blockIdx.x;
  const float* r = sc + row*(long)S;
  int lane = threadIdx.x;
  float vals[NV];
  float mx = -1e30f;
  #pragma unroll
  for (int i=0;i<NV;i++){ vals[i] = r[lane + i*64] * 0.08838834764831845f; mx = fmaxf(mx, vals[i]); }
  #pragma unroll
  for (int o=32;o;o>>=1) mx = fmaxf(mx, __shfl_xor(mx, o));
  float sum = 0.f;
  #pragma unroll
  for (int i=0;i<NV;i++){ vals[i] = expf(vals[i]-mx); sum += vals[i]; }
  #pragma unroll
  for (int o=32;o;o>>=1) sum += __shfl_xor(sum, o);
  float inv = 1.f/sum;
  #pragma unroll
  for (int i=0;i<NV;i++) at[row*(long)S + lane + i*64] = f2bf(vals[i]*inv);
}

// ----------------- generic batched bf16 MFMA GEMM (attention path) ----------
// r7-proven schedule: stage(t+1); vmcnt(8); barrier; compute; barrier.
template<int MODE>
__global__ __launch_bounds__(256)
void gemm_kernel(const unsigned short* __restrict__ A, int lda, long sAb, long sAh,
                 const unsigned short* __restrict__ Bt, int ldb, long sBb, long sBh,
                 void* __restrict__ Cout, int ldc, long sCb, long sCh,
                 const float* __restrict__ bias, long sbias,
                 int zshift, int zmask,
                 int M, int N, int K)
{
  __shared__ unsigned short AB[2][2][128*64];
  int z = blockIdx.z;
  int zb = z & zmask, zh = z >> zshift;
  const unsigned short* Az = A + (long)zb*sAb + (long)zh*sAh;
  const unsigned short* Bz = Bt + (long)zb*sBb + (long)zh*sBh;
  const float* biasz = bias ? (bias + (long)zh*sbias) : nullptr;
  int m0 = blockIdx.y*128, n0 = blockIdx.x*128;
  int tid = threadIdx.x;
  int lane = tid & 63, wid = tid >> 6;
  int wm = wid >> 1, wn = wid & 1;
  f32x4 zero4 = {0.f,0.f,0.f,0.f};
  f32x4 acc[4][4];
  #pragma unroll
  for (int m=0;m<4;m++)
    #pragma unroll
    for (int n=0;n<4;n++)
      acc[m][n] = zero4;
  const int r16 = lane & 15, kq = lane >> 4;

  auto stage = [&](int buf, int k0){
    #pragma unroll
    for (int i=0;i<4;i++){
      int chunk = i*256 + tid;                 // 1024 chunks of 16B
      int row = chunk >> 3, c = chunk & 7;
      int cg = (c ^ (row & 7)) * 8;            // pre-swizzled global col (elems)
      int gm = m0 + row; gm = gm < M ? gm : M-1;
      GLOAD(Az + (long)gm*lda + k0 + cg, AB[buf][0] + (i*256 + wid*64)*8);
    }
    #pragma unroll
    for (int i=0;i<4;i++){
      int chunk = i*256 + tid;
      int row = chunk >> 3, c = chunk & 7;
      int cg = (c ^ (row & 7)) * 8;
      int gn = n0 + row; gn = gn < N ? gn : N-1;
      GLOAD(Bz + (long)gn*ldb + k0 + cg, AB[buf][1] + (i*256 + wid*64)*8);
    }
  };

  int NT = K >> 6;
  stage(0, 0);
  for (int t = 0; t < NT; t++){
    if (t + 1 < NT){
      stage((t+1)&1, (t+1)*64);
      asm volatile("s_waitcnt vmcnt(8)" ::: "memory");
    } else {
      asm volatile("s_waitcnt vmcnt(0)" ::: "memory");
    }
    __builtin_amdgcn_s_barrier();
    const unsigned short* As = AB[t&1][0];
    const unsigned short* Bs = AB[t&1][1];
    #pragma unroll
    for (int kk=0; kk<64; kk+=32){
      short8 af[4], bfr[4];
      int kb = (kk + kq*8) * 2;
      #pragma unroll
      for (int m=0;m<4;m++){
        int row = wm*64 + m*16 + r16;
        af[m] = *(const short8*)((const char*)As + row*128 + (kb ^ ((row & 7) << 4)));
      }
      #pragma unroll
      for (int n=0;n<4;n++){
        int row = wn*64 + n*16 + r16;
        bfr[n] = *(const short8*)((const char*)Bs + row*128 + (kb ^ ((row & 7) << 4)));
      }
      #pragma unroll
      for (int m=0;m<4;m++)
        #pragma unroll
        for (int n=0;n<4;n++)
          acc[m][n] = __builtin_amdgcn_mfma_f32_16x16x32_bf16(af[m], bfr[n], acc[m][n], 0, 0, 0);
    }
    __builtin_amdgcn_s_barrier();
  }
  #pragma unroll
  for (int n=0;n<4;n++){
    int col = n0 + wn*64 + n*16 + r16;
    if (col >= N) continue;
    float bvv = 0.f;
    if (MODE != 0 && biasz != nullptr) bvv = biasz[col];
    #pragma unroll
    for (int m=0;m<4;m++){
      #pragma unroll
      for (int e=0;e<4;e++){
        int row = m0 + wm*64 + m*16 + kq*4 + e;
        if (row >= M) continue;
        float vv = acc[m][n][e] + bvv;
        long cidx = (long)zb*sCb + (long)zh*sCh + (long)row*ldc + col;
        if (MODE == 0)      ((float*)Cout)[cidx] = vv;
        else                ((unsigned short*)Cout)[cidx] = f2bf(vv);
      }
    }
  }
}

// ----------------- static-shape 128-tile GEMM (Wo / FFN2) -------------------
// r7-proven schedule, natural block order, no setprio.
// MODE 3: +bias, += into fp32 C
template<int MODE, int Mt, int Nt, int Kt, long SBH, long SCH, int BIASST>
__global__ __launch_bounds__(256)
void gemm_big(const unsigned short* __restrict__ A,
              const unsigned short* __restrict__ Bt,
              void* __restrict__ Cout,
              const float* __restrict__ bias)
{
  __shared__ char shraw[2][32768];              // dbuf: As 16KB + Bs 16KB each
  int zh = blockIdx.z;
  const unsigned short* Bz = Bt + (long)zh*SBH;
  const float* biasz = bias + (long)zh*BIASST;
  int m0 = blockIdx.y*128, n0 = blockIdx.x*128;
  int tid = threadIdx.x;
  int lane = tid & 63, wid = tid >> 6;
  int wm = wid >> 1, wn = wid & 1;
  f32x4 zero4 = {0.f,0.f,0.f,0.f};
  f32x4 acc[4][4];
  #pragma unroll
  for (int m=0;m<4;m++)
    #pragma unroll
    for (int n=0;n<4;n++)
      acc[m][n] = zero4;
  const int r16 = lane & 15, kq = lane >> 4;

  const unsigned short* pA[4];
  const unsigned short* pB[4];
  #pragma unroll
  for (int i=0;i<4;i++){
    int chunk = i*256 + tid;
    int row = chunk >> 3, c = chunk & 7;
    int cg = (c ^ (row & 7)) * 8;
    pA[i] = A  + (long)(m0 + row)*Kt + cg;
    pB[i] = Bz + (long)(n0 + row)*Kt + cg;
  }
  auto stage = [&](int buf, int k0){
    unsigned short* As = (unsigned short*)shraw[buf];
    #pragma unroll
    for (int i=0;i<4;i++) GLOAD(pA[i] + k0, As + (i*256 + wid*64)*8);
    #pragma unroll
    for (int i=0;i<4;i++) GLOAD(pB[i] + k0, As + 8192 + (i*256 + wid*64)*8);
  };

  constexpr int NT = Kt/64;
  stage(0, 0);
  for (int t = 0; t < NT; t++){
    if (t + 1 < NT){
      stage((t+1)&1, (t+1)*64);
      asm volatile("s_waitcnt vmcnt(8)" ::: "memory");
    } else {
      asm volatile("s_waitcnt vmcnt(0)" ::: "memory");
    }
    __builtin_amdgcn_s_barrier();
    const unsigned short* As = (const unsigned short*)shraw[t&1];
    const unsigned short* Bs = As + 8192;
    #pragma unroll
    for (int kk=0; kk<64; kk+=32){
      short8 af[4], bfr[4];
      int kb = (kk + kq*8) * 2;
      #pragma unroll
      for (int m=0;m<4;m++){
        int row = wm*64 + m*16 + r16;
        af[m] = *(const short8*)((const char*)As + row*128 + (kb ^ ((row & 7) << 4)));
      }
      #pragma unroll
      for (int n=0;n<4;n++){
        int row = wn*64 + n*16 + r16;
        bfr[n] = *(const short8*)((const char*)Bs + row*128 + (kb ^ ((row & 7) << 4)));
      }
      #pragma unroll
      for (int m=0;m<4;m++)
        #pragma unroll
        for (int n=0;n<4;n++)
          acc[m][n] = __builtin_amdgcn_mfma_f32_16x16x32_bf16(af[m], bfr[n], acc[m][n], 0, 0, 0);
    }
    __builtin_amdgcn_s_barrier();
  }

  // MODE 3: fp32 accumulate, two 64-row phases through LDS (stride 136 floats)
  float* shf = (float*)&shraw[0][0];
  #pragma unroll
  for (int ph=0; ph<2; ph++){
    __syncthreads();
    if (wm == ph){
      #pragma unroll
      for (int n=0;n<4;n++){
        int col = wn*64 + n*16 + r16;
        float bvv = biasz[n0 + col];
        #pragma unroll
        for (int m=0;m<4;m++){
          #pragma unroll
          for (int e=0;e<4;e++){
            int rl = m*16 + kq*4 + e;
            shf[rl*136 + col] = acc[m][n][e] + bvv;
          }
        }
      }
    }
    __syncthreads();
    #pragma unroll
    for (int i=0;i<8;i++){
      int chunk = i*256 + tid;                // 2048 chunks of 4 floats
      int row = chunk >> 5, col = (chunk & 31)*4;
      float4 vv = *(const float4*)(shf + row*136 + col);
      float* cp = (float*)Cout + (long)(m0 + ph*64 + row)*Nt + n0 + col;
      float4 o = *(const float4*)cp;
      o.x += vv.x; o.y += vv.y; o.z += vv.z; o.w += vv.w;
      *(float4*)cp = o;
    }
  }
}

// ----------- 256x256 GEMM, r7 2-phase schedule (QKV merged / FFN1) ----------
// 512 threads = 8 waves (2M x 4N), per-wave C = 128x64 (acc[8][4]).
// LDS 128KB: buf b at b*64KB {A 32KB, B 32KB}. K-loop schedule identical to
// gemm_big (stage(t+1) = 8 GLOADs; vmcnt(8); barrier; 64 MFMA; barrier).
// Geometry/staging/epilogue reused from the r8 kernel that PASSED correctness.
// MODE 1: +bias -> bf16 (SPLITZ: N spans [3][1024] projections) | MODE 2: GELU.
template<int MODE, int Mt, int Nt, int Kt, int SPLITZ, long SBH, long SCH>
__global__ __launch_bounds__(512)
void gemm256(const unsigned short* __restrict__ A,
             const unsigned short* __restrict__ Bt,
             void* __restrict__ Cout,
             const float* __restrict__ bias)
{
  __shared__ char lds[131072];
  int tid = threadIdx.x;
  int lane = tid & 63, w = tid >> 6;
  int wm = w >> 2, wn = w & 3;
  int r16 = lane & 15, kq = lane >> 4;
  int m0 = blockIdx.y * 256, n0 = blockIdx.x * 256;

  const unsigned short* Bz = SPLITZ ? (Bt + (long)(n0 >> 10) * SBH) : Bt;
  int nloc = SPLITZ ? (n0 & 1023) : n0;

  const unsigned short* pA[4];
  const unsigned short* pB[4];
  #pragma unroll
  for (int j=0;j<4;j++){
    int chunk = j*512 + tid;          // 2048 chunks of 16B per 256x64 tile
    int row = chunk >> 3, c = chunk & 7;
    int cg = (c ^ (row & 7)) * 8;     // pre-swizzled global col (elems)
    pA[j] = A  + (long)(m0 + row)*Kt + cg;
    pB[j] = Bz + (long)(nloc + row)*Kt + cg;
  }
  auto stage = [&](int buf, int k0){
    char* base = lds + buf*65536;
    #pragma unroll
    for (int j=0;j<4;j++) GLOAD(pA[j] + k0, base + (j*512 + w*64)*16);
    #pragma unroll
    for (int j=0;j<4;j++) GLOAD(pB[j] + k0, base + 32768 + (j*512 + w*64)*16);
  };

  f32x4 acc[8][4];
  f32x4 z4 = {0.f,0.f,0.f,0.f};
  #pragma unroll
  for (int m=0;m<8;m++)
    #pragma unroll
    for (int n=0;n<4;n++)
      acc[m][n] = z4;

  constexpr int NT = Kt/64;
  stage(0, 0);
  for (int t = 0; t < NT; t++){
    if (t + 1 < NT){
      stage((t+1)&1, (t+1)*64);
      asm volatile("s_waitcnt vmcnt(8)" ::: "memory");
    } else {
      asm volatile("s_waitcnt vmcnt(0)" ::: "memory");
    }
    __builtin_amdgcn_s_barrier();
    const char* Ac = lds + (t&1)*65536;
    const char* Bc = Ac + 32768;
    #pragma unroll
    for (int kk=0; kk<64; kk+=32){
      short8 af[8], bfv[4];
      int kb = (kk + kq*8)*2;
      #pragma unroll
      for (int m=0;m<8;m++){
        int row = wm*128 + m*16 + r16;
        af[m] = *(const short8*)(Ac + row*128 + (kb ^ ((row&7)<<4)));
      }
      #pragma unroll
      for (int n=0;n<4;n++){
        int row = wn*64 + n*16 + r16;
        bfv[n] = *(const short8*)(Bc + row*128 + (kb ^ ((row&7)<<4)));
      }
      #pragma unroll
      for (int m=0;m<8;m++)
        #pragma unroll
        for (int n=0;n<4;n++)
          acc[m][n] = __builtin_amdgcn_mfma_f32_16x16x32_bf16(af[m], bfv[n], acc[m][n], 0, 0, 0);
    }
    __builtin_amdgcn_s_barrier();
  }

  // ---- epilogue: 2 phases of 128 rows through LDS, coalesced short8 stores
  // (verified in r8: full 128x256 coverage per phase)
  unsigned short* ep = (unsigned short*)lds;     // 128 x 264 shorts = 66KB
  #pragma unroll
  for (int ph=0; ph<2; ph++){
    if (wm == ph){
      #pragma unroll
      for (int n=0;n<4;n++){
        int col = wn*64 + n*16 + r16;
        float bvv = bias[n0 + col];
        #pragma unroll
        for (int m=0;m<8;m++){
          #pragma unroll
          for (int e=0;e<4;e++){
            int rl = m*16 + kq*4 + e;            // 0..127
            float vv = acc[m][n][e] + bvv;
            if (MODE == 2) vv = 0.5f*vv*(1.f + erff(vv*0.7071067811865475f));
            ep[rl*264 + col] = f2bf(vv);
          }
        }
      }
    }
    __syncthreads();
    #pragma unroll
    for (int i=0;i<8;i++){
      int chunk = i*512 + tid;                   // 4096 chunks of 8 shorts
      int row = chunk >> 5, col = (chunk & 31)*8;
      short8 v8 = *(const short8*)(ep + row*264 + col);
      int grow = m0 + ph*128 + row;
      if (SPLITZ){
        int cg = n0 + col; int zz = cg >> 10; int cl = cg & 1023;
        *(short8*)((unsigned short*)Cout + (long)zz*SCH + (long)grow*1024 + cl) = v8;
      } else {
        *(short8*)((unsigned short*)Cout + (long)grow*Nt + n0 + col) = v8;
      }
    }
    __syncthreads();
  }
}

// ---------------------------------------------------------------------------
extern "C" void kernel_launch(void* const* d_in, const int* in_sizes, int n_in,
                              void* d_out, int out_size, void* d_ws, size_t ws_size,
                              hipStream_t stream){
  const int*   tokens = (const int*)  d_in[0];
  const float* embedp = (const float*)d_in[1];
  const float* pos    = (const float*)d_in[2];
  const float* Wq  = (const float*)d_in[3];
  const float* bq  = (const float*)d_in[4];
  const float* Wk  = (const float*)d_in[5];
  const float* bk  = (const float*)d_in[6];
  const float* Wv  = (const float*)d_in[7];
  const float* bv  = (const float*)d_in[8];
  const float* Wo  = (const float*)d_in[9];
  const float* bo  = (const float*)d_in[10];
  const float* ln1g= (const float*)d_in[11];
  const float* ln1b= (const float*)d_in[12];
  const float* ln2g= (const float*)d_in[13];
  const float* ln2b= (const float*)d_in[14];
  const float* W1  = (const float*)d_in[15];
  const float* b1  = (const float*)d_in[16];
  const float* W2  = (const float*)d_in[17];
  const float* b2  = (const float*)d_in[18];
  const float* gates=(const float*)d_in[19];
  const float* lnfg= (const float*)d_in[20];
  const float* lnfb= (const float*)d_in[21];
  float* out = (float*)d_out;

  char* base = (char*)d_ws;
  size_t off = 0;
  auto take = [&](size_t bytes)->char*{
    char* p = base + off;
    off = (off + bytes + 255) & ~(size_t)255;
    return p;
  };
  unsigned short* WqT = (unsigned short*)take((size_t)Ln*Dn*Dn*2);
  unsigned short* WkT = (unsigned short*)take((size_t)Ln*Dn*Dn*2);   // contiguous after WqT
  unsigned short* WvT = (unsigned short*)take((size_t)Ln*Dn*Dn*2);   // contiguous after WkT
  unsigned short* WoT = (unsigned short*)take((size_t)Ln*Dn*Dn*2);
  unsigned short* W1T = (unsigned short*)take((size_t)Ln*Dn*Fn*2);
  unsigned short* W2T = (unsigned short*)take((size_t)Ln*Dn*Fn*2);
  unsigned short* G   = (unsigned short*)take((size_t)Ln*Hn*Tn*Tn*2);
  float*          cbuf= (float*)take((size_t)Ln*Hn*Tn*4);
  float*          bqkv= (float*)take((size_t)Ln*3*Dn*4);
  float*          x   = (float*)take((size_t)Bn*Tn*Dn*4);
  unsigned short* hbuf= (unsigned short*)take((size_t)Bn*Tn*Dn*2);
  unsigned short* q   = (unsigned short*)take((size_t)Bn*Tn*Dn*2);   // q,k,v contiguous
  unsigned short* k   = (unsigned short*)take((size_t)Bn*Tn*Dn*2);
  unsigned short* v   = (unsigned short*)take((size_t)Bn*Tn*Dn*2);
  unsigned short* kp  = (unsigned short*)take((size_t)Bn*1920*HDn*2);
  unsigned short* vTp = (unsigned short*)take((size_t)Bn*1920*HDn*2);
  unsigned short* ao  = (unsigned short*)take((size_t)Bn*Tn*Dn*2);
  unsigned short* ff1 = (unsigned short*)take((size_t)Bn*Tn*Fn*2);
  if (off > ws_size) return;   // workspace insufficient: bail (output stays 0)
  // scores/attn alias the (temporally dead) ff1 buffer during attention.
  float*          scoresA = (float*)ff1;
  unsigned short* attnA   = (unsigned short*)(scoresA + (size_t)2*Bn*Tn*512);
  // oT (full 8-head [h][b][d][t], 16 MB) aliases k: k is dead after pool,
  // and q/k/v are rewritten only at the next layer's QKV (after gating+Wo).
  unsigned short* oT = k;

  // ---- one-time-per-launch precompute ----
  transpose_w<<<dim3(Dn/32, Dn/32, Ln), 256, 0, stream>>>(Wq, WqT, Dn, Dn);
  transpose_w<<<dim3(Dn/32, Dn/32, Ln), 256, 0, stream>>>(Wk, WkT, Dn, Dn);
  transpose_w<<<dim3(Dn/32, Dn/32, Ln), 256, 0, stream>>>(Wv, WvT, Dn, Dn);
  transpose_w<<<dim3(Dn/32, Dn/32, Ln), 256, 0, stream>>>(Wo, WoT, Dn, Dn);
  transpose_w<<<dim3(Fn/32, Dn/32, Ln), 256, 0, stream>>>(W1, W1T, Dn, Fn);
  transpose_w<<<dim3(Dn/32, Fn/32, Ln), 256, 0, stream>>>(W2, W2T, Fn, Dn);
  pack_bias<<<(Ln*3*Dn)/256, 256, 0, stream>>>(bq, bk, bv, bqkv);
  ckern<<<Ln*Hn, 512, 0, stream>>>(gates, cbuf);
  gfill<<<(Ln*Hn*Tn*Tn)/256, 256, 0, stream>>>(cbuf, G);
  embed_kernel<<<Bn*Tn, 256, 0, stream>>>(tokens, embedp, pos, x);

  const int pref[8] = {0,512,1024,1280,1536,1664,1792,1856};
  const int MT = Bn*Tn;   // 8192

  for (int l=0; l<Ln; l++){
    // LN1 -> hbuf (bf16)
    ln_kernel<1><<<MT, 256, 0, stream>>>(x, ln1g + l*Dn, ln1b + l*Dn, hbuf);
    // QKV: one merged 256-tile GEMM over N=3072
    gemm256<1, 8192, 3072, 1024, 1, (long)Ln*Dn*Dn, (long)Bn*Tn*Dn>
        <<<dim3(12, 32), 512, 0, stream>>>(
        hbuf, WqT + (size_t)l*Dn*Dn, q, bqkv + (size_t)l*3*Dn);
    // pool K,V  (k,v dead afterwards; oT aliases k)
    pool_kernel<<<((long)Bn*1920*HDn + 255)/256, 256, 0, stream>>>(k, v, kp, vTp);

    for (int g=0; g<4; g++){
      int h0 = 2*g;
      int S  = Tn >> g;
      long koff = (long)Bn*HDn*pref[h0];
      // scores[zh,zb,t,s] = q_h . kp_h   (z = zh*16 + zb)
      gemm_kernel<0><<<dim3((S+127)/128, Tn/128, 32), 256, 0, stream>>>(
          q + h0*HDn, Dn, (long)Tn*Dn, (long)HDn,
          kp + koff, HDn, (long)S*HDn, (long)Bn*HDn*S,
          scoresA, S, (long)Tn*S, (long)Bn*Tn*S,
          nullptr, 0L, 4, 15,
          Tn, S, HDn);
      // softmax -> attn (bf16), 2*B*T rows
      switch (S){
        case 512: softmax_kernel<512><<<2*MT, 64, 0, stream>>>(scoresA, attnA); break;
        case 256: softmax_kernel<256><<<2*MT, 64, 0, stream>>>(scoresA, attnA); break;
        case 128: softmax_kernel<128><<<2*MT, 64, 0, stream>>>(scoresA, attnA); break;
        default:  softmax_kernel< 64><<<2*MT, 64, 0, stream>>>(scoresA, attnA); break;
      }
      // oT[h0+zh][zb][d][t] = sum_s vTp[h,b,d,s] * attn[zh,zb,t,s]
      gemm_kernel<1><<<dim3(Tn/128, HDn/128, 32), 256, 0, stream>>>(
          vTp + koff, S, (long)HDn*S, (long)Bn*HDn*S,
          attnA, S, (long)Tn*S, (long)Bn*Tn*S,
          oT + (size_t)h0*Bn*HDn*Tn, Tn, (long)HDn*Tn, (long)Bn*HDn*Tn,
          nullptr, 0L, 4, 15,
          HDn, Tn, S);
    }
    // spectral gating, all 8 heads in ONE launch (z = zh*16+zb, zh=head):
    // ao[zb, t, zh*128+d] = sum_s G[l,zh][t,s] * oT[zh][zb][d][s]
    gemm_kernel<1><<<dim3(1, Tn/128, 128), 256, 0, stream>>>(
        G + (size_t)(l*Hn)*Tn*Tn, Tn, 0L, (long)Tn*Tn,
        oT, Tn, (long)HDn*Tn, (long)Bn*HDn*Tn,
        ao, Dn, (long)Tn*Dn, (long)HDn,
        nullptr, 0L, 4, 15,
        Tn, HDn, Tn);
    // Wo projection + residual into x (fp32)
    gemm_big<3, 8192, Dn, Dn, 0L, 0L, 0>
        <<<dim3(Dn/128, MT/128, 1), 256, 0, stream>>>(
        ao, WoT + (size_t)l*Dn*Dn, x, bo + l*Dn);
    // LN2 -> hbuf
    ln_kernel<1><<<MT, 256, 0, stream>>>(x, ln2g + l*Dn, ln2b + l*Dn, hbuf);
    // FFN1: GELU(h@W1+b1) -> ff1 (bf16)   [scores/attn alias is dead now]
    gemm256<2, 8192, Fn, 1024, 0, 0L, 0L>
        <<<dim3(16, 32), 512, 0, stream>>>(
        hbuf, W1T + (size_t)l*Dn*Fn, ff1, b1 + l*Fn);
    // FFN2 + residual into x
    gemm_big<3, 8192, Dn, Fn, 0L, 0L, 0>
        <<<dim3(Dn/128, MT/128, 1), 256, 0, stream>>>(
        ff1, W2T + (size_t)l*Dn*Fn, x, b2 + l*Dn);
  }
  // final LN -> d_out (fp32)
  ln_kernel<0><<<MT, 256, 0, stream>>>(x, lnfg, lnfb, out);
}

// Round 12
// 3117.794 us; speedup vs baseline: 1.1330x; 1.0329x over previous
//
#include <hip/hip_runtime.h>
#include <hip/hip_bf16.h>
#include <math.h>

#define Bn 16
#define Tn 512
#define Dn 1024
#define Hn 8
#define Ln 6
#define Fn 4096
#define HDn 128

typedef __attribute__((ext_vector_type(8))) short short8;
typedef __attribute__((ext_vector_type(4))) float f32x4;

__device__ __forceinline__ float bf2f(unsigned short u){
  union{float f; unsigned int i;} c; c.i = ((unsigned int)u)<<16; return c.f;
}
__device__ __forceinline__ unsigned short f2bf(float f){
  union{float f; unsigned int i;} c; c.f=f;
  unsigned int r = c.i + 0x7fffu + ((c.i>>16)&1u);
  return (unsigned short)(r>>16);
}

#define GLOAD(gp, lp) __builtin_amdgcn_global_load_lds( \
    (const __attribute__((address_space(1))) void*)(const void*)(gp), \
    (__attribute__((address_space(3))) void*)(void*)(lp), 16, 0, 0)

// ---------------- embedding: x[b,t,:] = embed[tok] + pos[t] ----------------
__global__ __launch_bounds__(256) void embed_kernel(
    const int* __restrict__ tok, const float* __restrict__ emb,
    const float* __restrict__ pos, float* __restrict__ x){
  long row = blockIdx.x;                 // b*T + t
  int t = (int)(row & (Tn-1));
  int tk = tok[row];
  int d = threadIdx.x*4;
  float4 e = *(const float4*)(emb + (long)tk*Dn + d);
  float4 p = *(const float4*)(pos + (long)t*Dn + d);
  float4 r; r.x=e.x+p.x; r.y=e.y+p.y; r.z=e.z+p.z; r.w=e.w+p.w;
  *(float4*)(x + row*(long)Dn + d) = r;
}

// ---------------- LayerNorm over D=1024 (one block per row) ----------------
template<int OUTBF>
__global__ __launch_bounds__(256) void ln_kernel(
    const float* __restrict__ x, const float* __restrict__ g,
    const float* __restrict__ b, void* __restrict__ outp){
  long row = blockIdx.x;
  const float* xr = x + row*(long)Dn;
  int tid = threadIdx.x;
  float4 v4 = *(const float4*)(xr + tid*4);
  float s  = v4.x+v4.y+v4.z+v4.w;
  float s2 = v4.x*v4.x + v4.y*v4.y + v4.z*v4.z + v4.w*v4.w;
  #pragma unroll
  for (int o=32;o;o>>=1){ s += __shfl_xor(s,o); s2 += __shfl_xor(s2,o); }
  __shared__ float rs[4], rs2[4];
  int w = tid>>6;
  if ((tid&63)==0){ rs[w]=s; rs2[w]=s2; }
  __syncthreads();
  s  = rs[0]+rs[1]+rs[2]+rs[3];
  s2 = rs2[0]+rs2[1]+rs2[2]+rs2[3];
  float mu  = s*(1.f/Dn);
  float var = s2*(1.f/Dn) - mu*mu;
  float rstd = rsqrtf(var + 1e-5f);
  float4 gg = *(const float4*)(g + tid*4);
  float4 bb = *(const float4*)(b + tid*4);
  float o0 = (v4.x-mu)*rstd*gg.x + bb.x;
  float o1 = (v4.y-mu)*rstd*gg.y + bb.y;
  float o2 = (v4.z-mu)*rstd*gg.z + bb.z;
  float o3 = (v4.w-mu)*rstd*gg.w + bb.w;
  if (OUTBF){
    unsigned short* o = (unsigned short*)outp + row*(long)Dn + tid*4;
    o[0]=f2bf(o0); o[1]=f2bf(o1); o[2]=f2bf(o2); o[3]=f2bf(o3);
  } else {
    float* o = (float*)outp + row*(long)Dn + tid*4;
    o[0]=o0; o[1]=o1; o[2]=o2; o[3]=o3;
  }
}

// ------------- weight transpose+convert: W[K][N] f32 -> WT[N][K] bf16 -------
__global__ __launch_bounds__(256) void transpose_w(
    const float* __restrict__ W, unsigned short* __restrict__ WT, int Kd, int Nd){
  __shared__ float tile[32][33];
  long lofs = (long)blockIdx.z * Kd * Nd;
  int n0 = blockIdx.x*32, k0 = blockIdx.y*32;
  int tx = threadIdx.x & 31, ty = threadIdx.x >> 5;   // ty 0..7
  #pragma unroll
  for (int i=0;i<4;i++){
    int kk = k0 + ty + i*8;
    tile[ty+i*8][tx] = W[lofs + (long)kk*Nd + n0 + tx];
  }
  __syncthreads();
  #pragma unroll
  for (int i=0;i<4;i++){
    int nn = n0 + ty + i*8;
    WT[lofs + (long)nn*Kd + k0 + tx] = f2bf(tile[tx][ty+i*8]);
  }
}

// ---- pack QKV biases into bqkv[L][3][D] for the batched QKV GEMM ----------
__global__ __launch_bounds__(256) void pack_bias(
    const float* __restrict__ bq, const float* __restrict__ bk,
    const float* __restrict__ bv, float* __restrict__ bqkv){
  int i = blockIdx.x*256 + threadIdx.x;   // l*3*Dn + w*Dn + d
  int l = i / (3*Dn); int r = i - l*3*Dn; int w = r / Dn; int d = r - w*Dn;
  const float* src = (w==0)? bq : ((w==1)? bk : bv);
  bqkv[i] = src[l*Dn + d];
}

// ------- circulant kernel c = irfft(gate per rfft-bin), per (layer,head) ----
__global__ __launch_bounds__(512) void ckern(
    const float* __restrict__ gates, float* __restrict__ cbuf){
  int lh = blockIdx.x;                   // l*H + h
  __shared__ float gb[16];
  if (threadIdx.x < 16) gb[threadIdx.x] = gates[lh*16 + threadIdx.x];
  __syncthreads();
  int m = threadIdx.x;                   // 0..511
  float acc = gb[0];                     // bin 0, weight 1, band 0
  for (int j=1;j<256;j++){
    int band = (j*16)/257;               // (j*BANDS)//nb
    int kmod = (j*m) & 511;              // exact phase reduction
    acc += 2.f*gb[band]*cosf(1.2271846303085129e-2f * (float)kmod); // 2pi/512
  }
  acc += gb[15] * ((m & 1) ? -1.f : 1.f);   // Nyquist bin, band 15
  cbuf[lh*512 + m] = acc * (1.f/512.f);
}

// --------- materialize G[l,h,t,s] = c[(t-s) mod 512] as bf16 ---------------
__global__ __launch_bounds__(256) void gfill(
    const float* __restrict__ cbuf, unsigned short* __restrict__ G){
  long idx = (long)blockIdx.x*256 + threadIdx.x;   // grid sized exactly
  int lh = (int)(idx >> 18);
  int rem = (int)(idx & 262143);
  int t = rem >> 9, s = rem & 511;
  G[idx] = f2bf(cbuf[lh*512 + ((t - s) & 511)]);
}

// --------- pool K,V per head: kp[b,s,d] mean, vTp[b,d,s] mean ---------------
__global__ __launch_bounds__(256) void pool_kernel(
    const unsigned short* __restrict__ kin, const unsigned short* __restrict__ vin,
    unsigned short* __restrict__ kp, unsigned short* __restrict__ vTp){
  long idx = (long)blockIdx.x*256 + threadIdx.x;
  if (idx >= (long)Bn*1920*HDn) return;
  long rem = idx; int hh = 0; int S = 512;
  for (hh=0; hh<8; hh++){
    S = 512 >> (hh>>1);
    long seg = (long)Bn*S*HDn;
    if (rem < seg) break;
    rem -= seg;
  }
  int r = 512 / S;
  int d = (int)(rem % HDn);
  long t2 = rem / HDn;
  int s = (int)(t2 % S);
  int b = (int)(t2 / S);
  const unsigned short* kb = kin + ((long)(b*Tn + s*r))*Dn + hh*HDn + d;
  const unsigned short* vb = vin + ((long)(b*Tn + s*r))*Dn + hh*HDn + d;
  float ks=0.f, vs=0.f;
  for (int j=0;j<r;j++){ ks += bf2f(kb[(long)j*Dn]); vs += bf2f(vb[(long)j*Dn]); }
  float inv = 1.f/(float)r;
  int pref=0;
  for (int g2=0; g2<hh; g2++) pref += 512 >> (g2>>1);
  long segb = (long)Bn*HDn*pref;
  kp [segb + ((long)b*S + s)*HDn + d] = f2bf(ks*inv);
  vTp[segb + ((long)b*HDn + d)*S + s] = f2bf(vs*inv);
}

// --------- row softmax (scale 1/sqrt(128)), fp32 in -> bf16 out -------------
// 256 threads = 4 waves, one row per wave (rows need no cross-wave reduce).
template<int S>
__global__ __launch_bounds__(256) void softmax_kernel(
    const float* __restrict__ sc, unsigned short* __restrict__ at){
  const int NV = S/64;
  long row = (long)blockIdx.x*4 + (threadIdx.x >> 6);
  const float* r = sc + row*(long)S;
  int lane = threadIdx.x & 63;
  float vals[NV];
  float mx = -1e30f;
  #pragma unroll
  for (int i=0;i<NV;i++){ vals[i] = r[lane + i*64] * 0.08838834764831845f; mx = fmaxf(mx, vals[i]); }
  #pragma unroll
  for (int o=32;o;o>>=1) mx = fmaxf(mx, __shfl_xor(mx, o));
  float sum = 0.f;
  #pragma unroll
  for (int i=0;i<NV;i++){ vals[i] = expf(vals[i]-mx); sum += vals[i]; }
  #pragma unroll
  for (int o=32;o;o>>=1) sum += __shfl_xor(sum, o);
  float inv = 1.f/sum;
  #pragma unroll
  for (int i=0;i<NV;i++) at[row*(long)S + lane + i*64] = f2bf(vals[i]*inv);
}

// ----------------- generic batched bf16 MFMA GEMM (attention path) ----------
// r7-proven schedule: stage(t+1); vmcnt(8); barrier; compute; barrier.
template<int MODE>
__global__ __launch_bounds__(256)
void gemm_kernel(const unsigned short* __restrict__ A, int lda, long sAb, long sAh,
                 const unsigned short* __restrict__ Bt, int ldb, long sBb, long sBh,
                 void* __restrict__ Cout, int ldc, long sCb, long sCh,
                 const float* __restrict__ bias, long sbias,
                 int zshift, int zmask,
                 int M, int N, int K)
{
  __shared__ unsigned short AB[2][2][128*64];
  int z = blockIdx.z;
  int zb = z & zmask, zh = z >> zshift;
  const unsigned short* Az = A + (long)zb*sAb + (long)zh*sAh;
  const unsigned short* Bz = Bt + (long)zb*sBb + (long)zh*sBh;
  const float* biasz = bias ? (bias + (long)zh*sbias) : nullptr;
  int m0 = blockIdx.y*128, n0 = blockIdx.x*128;
  int tid = threadIdx.x;
  int lane = tid & 63, wid = tid >> 6;
  int wm = wid >> 1, wn = wid & 1;
  f32x4 zero4 = {0.f,0.f,0.f,0.f};
  f32x4 acc[4][4];
  #pragma unroll
  for (int m=0;m<4;m++)
    #pragma unroll
    for (int n=0;n<4;n++)
      acc[m][n] = zero4;
  const int r16 = lane & 15, kq = lane >> 4;

  auto stage = [&](int buf, int k0){
    #pragma unroll
    for (int i=0;i<4;i++){
      int chunk = i*256 + tid;                 // 1024 chunks of 16B
      int row = chunk >> 3, c = chunk & 7;
      int cg = (c ^ (row & 7)) * 8;            // pre-swizzled global col (elems)
      int gm = m0 + row; gm = gm < M ? gm : M-1;
      GLOAD(Az + (long)gm*lda + k0 + cg, AB[buf][0] + (i*256 + wid*64)*8);
    }
    #pragma unroll
    for (int i=0;i<4;i++){
      int chunk = i*256 + tid;
      int row = chunk >> 3, c = chunk & 7;
      int cg = (c ^ (row & 7)) * 8;
      int gn = n0 + row; gn = gn < N ? gn : N-1;
      GLOAD(Bz + (long)gn*ldb + k0 + cg, AB[buf][1] + (i*256 + wid*64)*8);
    }
  };

  int NT = K >> 6;
  stage(0, 0);
  for (int t = 0; t < NT; t++){
    if (t + 1 < NT){
      stage((t+1)&1, (t+1)*64);
      asm volatile("s_waitcnt vmcnt(8)" ::: "memory");
    } else {
      asm volatile("s_waitcnt vmcnt(0)" ::: "memory");
    }
    __builtin_amdgcn_s_barrier();
    const unsigned short* As = AB[t&1][0];
    const unsigned short* Bs = AB[t&1][1];
    #pragma unroll
    for (int kk=0; kk<64; kk+=32){
      short8 af[4], bfr[4];
      int kb = (kk + kq*8) * 2;
      #pragma unroll
      for (int m=0;m<4;m++){
        int row = wm*64 + m*16 + r16;
        af[m] = *(const short8*)((const char*)As + row*128 + (kb ^ ((row & 7) << 4)));
      }
      #pragma unroll
      for (int n=0;n<4;n++){
        int row = wn*64 + n*16 + r16;
        bfr[n] = *(const short8*)((const char*)Bs + row*128 + (kb ^ ((row & 7) << 4)));
      }
      #pragma unroll
      for (int m=0;m<4;m++)
        #pragma unroll
        for (int n=0;n<4;n++)
          acc[m][n] = __builtin_amdgcn_mfma_f32_16x16x32_bf16(af[m], bfr[n], acc[m][n], 0, 0, 0);
    }
    __builtin_amdgcn_s_barrier();
  }
  #pragma unroll
  for (int n=0;n<4;n++){
    int col = n0 + wn*64 + n*16 + r16;
    if (col >= N) continue;
    float bvv = 0.f;
    if (MODE != 0 && biasz != nullptr) bvv = biasz[col];
    #pragma unroll
    for (int m=0;m<4;m++){
      #pragma unroll
      for (int e=0;e<4;e++){
        int row = m0 + wm*64 + m*16 + kq*4 + e;
        if (row >= M) continue;
        float vv = acc[m][n][e] + bvv;
        long cidx = (long)zb*sCb + (long)zh*sCh + (long)row*ldc + col;
        if (MODE == 0)      ((float*)Cout)[cidx] = vv;
        else                ((unsigned short*)Cout)[cidx] = f2bf(vv);
      }
    }
  }
}

// ----------------- static-shape 128-tile GEMM (all dense projections) -------
// r7-proven schedule, natural block order, no setprio.
// MODE 1: +bias -> bf16 | 2: +bias,GELU -> bf16 | 3: +bias, += into fp32 C
template<int MODE, int Mt, int Nt, int Kt, long SBH, long SCH, int BIASST>
__global__ __launch_bounds__(256)
void gemm_big(const unsigned short* __restrict__ A,
              const unsigned short* __restrict__ Bt,
              void* __restrict__ Cout,
              const float* __restrict__ bias)
{
  __shared__ char shraw[2][32768];              // dbuf: As 16KB + Bs 16KB each
  int zh = blockIdx.z;
  const unsigned short* Bz = Bt + (long)zh*SBH;
  const float* biasz = bias + (long)zh*BIASST;
  int m0 = blockIdx.y*128, n0 = blockIdx.x*128;
  int tid = threadIdx.x;
  int lane = tid & 63, wid = tid >> 6;
  int wm = wid >> 1, wn = wid & 1;
  f32x4 zero4 = {0.f,0.f,0.f,0.f};
  f32x4 acc[4][4];
  #pragma unroll
  for (int m=0;m<4;m++)
    #pragma unroll
    for (int n=0;n<4;n++)
      acc[m][n] = zero4;
  const int r16 = lane & 15, kq = lane >> 4;

  const unsigned short* pA[4];
  const unsigned short* pB[4];
  #pragma unroll
  for (int i=0;i<4;i++){
    int chunk = i*256 + tid;
    int row = chunk >> 3, c = chunk & 7;
    int cg = (c ^ (row & 7)) * 8;
    pA[i] = A  + (long)(m0 + row)*Kt + cg;
    pB[i] = Bz + (long)(n0 + row)*Kt + cg;
  }
  auto stage = [&](int buf, int k0){
    unsigned short* As = (unsigned short*)shraw[buf];
    #pragma unroll
    for (int i=0;i<4;i++) GLOAD(pA[i] + k0, As + (i*256 + wid*64)*8);
    #pragma unroll
    for (int i=0;i<4;i++) GLOAD(pB[i] + k0, As + 8192 + (i*256 + wid*64)*8);
  };

  constexpr int NT = Kt/64;
  stage(0, 0);
  for (int t = 0; t < NT; t++){
    if (t + 1 < NT){
      stage((t+1)&1, (t+1)*64);
      asm volatile("s_waitcnt vmcnt(8)" ::: "memory");
    } else {
      asm volatile("s_waitcnt vmcnt(0)" ::: "memory");
    }
    __builtin_amdgcn_s_barrier();
    const unsigned short* As = (const unsigned short*)shraw[t&1];
    const unsigned short* Bs = As + 8192;
    #pragma unroll
    for (int kk=0; kk<64; kk+=32){
      short8 af[4], bfr[4];
      int kb = (kk + kq*8) * 2;
      #pragma unroll
      for (int m=0;m<4;m++){
        int row = wm*64 + m*16 + r16;
        af[m] = *(const short8*)((const char*)As + row*128 + (kb ^ ((row & 7) << 4)));
      }
      #pragma unroll
      for (int n=0;n<4;n++){
        int row = wn*64 + n*16 + r16;
        bfr[n] = *(const short8*)((const char*)Bs + row*128 + (kb ^ ((row & 7) << 4)));
      }
      #pragma unroll
      for (int m=0;m<4;m++)
        #pragma unroll
        for (int n=0;n<4;n++)
          acc[m][n] = __builtin_amdgcn_mfma_f32_16x16x32_bf16(af[m], bfr[n], acc[m][n], 0, 0, 0);
    }
    __builtin_amdgcn_s_barrier();
  }

  if (MODE == 1 || MODE == 2){
    // bf16 tile via LDS (stride 136 shorts = 272B = 17*16B, rows 16B-aligned)
    unsigned short* shb = (unsigned short*)&shraw[0][0];
    #pragma unroll
    for (int n=0;n<4;n++){
      int col = wn*64 + n*16 + r16;
      float bvv = biasz[n0 + col];
      #pragma unroll
      for (int m=0;m<4;m++){
        #pragma unroll
        for (int e=0;e<4;e++){
          int row = wm*64 + m*16 + kq*4 + e;
          float vv = acc[m][n][e] + bvv;
          if (MODE == 2) vv = 0.5f*vv*(1.f + erff(vv*0.7071067811865475f));
          shb[row*136 + col] = f2bf(vv);
        }
      }
    }
    __syncthreads();
    // FULL 128x128 tile = 2048 chunks of 8 shorts
    #pragma unroll
    for (int i=0;i<8;i++){
      int chunk = i*256 + tid;
      int row = chunk >> 4, col = (chunk & 15)*8;
      short8 vv8 = *(const short8*)(shb + row*136 + col);
      *(short8*)((unsigned short*)Cout + (long)zh*SCH +
                 (long)(m0 + row)*Nt + n0 + col) = vv8;
    }
  } else {
    // MODE 3: fp32 accumulate, two 64-row phases through LDS (stride 136 floats)
    float* shf = (float*)&shraw[0][0];
    #pragma unroll
    for (int ph=0; ph<2; ph++){
      __syncthreads();
      if (wm == ph){
        #pragma unroll
        for (int n=0;n<4;n++){
          int col = wn*64 + n*16 + r16;
          float bvv = biasz[n0 + col];
          #pragma unroll
          for (int m=0;m<4;m++){
            #pragma unroll
            for (int e=0;e<4;e++){
              int rl = m*16 + kq*4 + e;
              shf[rl*136 + col] = acc[m][n][e] + bvv;
            }
          }
        }
      }
      __syncthreads();
      #pragma unroll
      for (int i=0;i<8;i++){
        int chunk = i*256 + tid;                // 2048 chunks of 4 floats
        int row = chunk >> 5, col = (chunk & 31)*4;
        float4 vv = *(const float4*)(shf + row*136 + col);
        float* cp = (float*)Cout + (long)(m0 + ph*64 + row)*Nt + n0 + col;
        float4 o = *(const float4*)cp;
        o.x += vv.x; o.y += vv.y; o.z += vv.z; o.w += vv.w;
        *(float4*)cp = o;
      }
    }
  }
}

// ---------------------------------------------------------------------------
extern "C" void kernel_launch(void* const* d_in, const int* in_sizes, int n_in,
                              void* d_out, int out_size, void* d_ws, size_t ws_size,
                              hipStream_t stream){
  const int*   tokens = (const int*)  d_in[0];
  const float* embedp = (const float*)d_in[1];
  const float* pos    = (const float*)d_in[2];
  const float* Wq  = (const float*)d_in[3];
  const float* bq  = (const float*)d_in[4];
  const float* Wk  = (const float*)d_in[5];
  const float* bk  = (const float*)d_in[6];
  const float* Wv  = (const float*)d_in[7];
  const float* bv  = (const float*)d_in[8];
  const float* Wo  = (const float*)d_in[9];
  const float* bo  = (const float*)d_in[10];
  const float* ln1g= (const float*)d_in[11];
  const float* ln1b= (const float*)d_in[12];
  const float* ln2g= (const float*)d_in[13];
  const float* ln2b= (const float*)d_in[14];
  const float* W1  = (const float*)d_in[15];
  const float* b1  = (const float*)d_in[16];
  const float* W2  = (const float*)d_in[17];
  const float* b2  = (const float*)d_in[18];
  const float* gates=(const float*)d_in[19];
  const float* lnfg= (const float*)d_in[20];
  const float* lnfb= (const float*)d_in[21];
  float* out = (float*)d_out;

  char* base = (char*)d_ws;
  size_t off = 0;
  auto take = [&](size_t bytes)->char*{
    char* p = base + off;
    off = (off + bytes + 255) & ~(size_t)255;
    return p;
  };
  unsigned short* WqT = (unsigned short*)take((size_t)Ln*Dn*Dn*2);
  unsigned short* WkT = (unsigned short*)take((size_t)Ln*Dn*Dn*2);   // contiguous after WqT
  unsigned short* WvT = (unsigned short*)take((size_t)Ln*Dn*Dn*2);   // contiguous after WkT
  unsigned short* WoT = (unsigned short*)take((size_t)Ln*Dn*Dn*2);
  unsigned short* W1T = (unsigned short*)take((size_t)Ln*Dn*Fn*2);
  unsigned short* W2T = (unsigned short*)take((size_t)Ln*Dn*Fn*2);
  unsigned short* G   = (unsigned short*)take((size_t)Ln*Hn*Tn*Tn*2);
  float*          cbuf= (float*)take((size_t)Ln*Hn*Tn*4);
  float*          bqkv= (float*)take((size_t)Ln*3*Dn*4);
  float*          x   = (float*)take((size_t)Bn*Tn*Dn*4);
  unsigned short* hbuf= (unsigned short*)take((size_t)Bn*Tn*Dn*2);
  unsigned short* q   = (unsigned short*)take((size_t)Bn*Tn*Dn*2);   // q,k,v contiguous
  unsigned short* k   = (unsigned short*)take((size_t)Bn*Tn*Dn*2);
  unsigned short* v   = (unsigned short*)take((size_t)Bn*Tn*Dn*2);
  unsigned short* kp  = (unsigned short*)take((size_t)Bn*1920*HDn*2);
  unsigned short* vTp = (unsigned short*)take((size_t)Bn*1920*HDn*2);
  unsigned short* ao  = (unsigned short*)take((size_t)Bn*Tn*Dn*2);
  unsigned short* ff1 = (unsigned short*)take((size_t)Bn*Tn*Fn*2);
  if (off > ws_size) return;   // workspace insufficient: bail (output stays 0)
  // scores/attn alias the (temporally dead) ff1 buffer during attention.
  float*          scoresA = (float*)ff1;
  unsigned short* attnA   = (unsigned short*)(scoresA + (size_t)2*Bn*Tn*512);
  // oT (full 8-head [h][b][d][t], 16 MB) aliases k: k is dead after pool,
  // and q/k/v are rewritten only at the next layer's QKV (after gating+Wo).
  unsigned short* oT = k;

  // ---- one-time-per-launch precompute ----
  transpose_w<<<dim3(Dn/32, Dn/32, Ln), 256, 0, stream>>>(Wq, WqT, Dn, Dn);
  transpose_w<<<dim3(Dn/32, Dn/32, Ln), 256, 0, stream>>>(Wk, WkT, Dn, Dn);
  transpose_w<<<dim3(Dn/32, Dn/32, Ln), 256, 0, stream>>>(Wv, WvT, Dn, Dn);
  transpose_w<<<dim3(Dn/32, Dn/32, Ln), 256, 0, stream>>>(Wo, WoT, Dn, Dn);
  transpose_w<<<dim3(Fn/32, Dn/32, Ln), 256, 0, stream>>>(W1, W1T, Dn, Fn);
  transpose_w<<<dim3(Dn/32, Fn/32, Ln), 256, 0, stream>>>(W2, W2T, Fn, Dn);
  pack_bias<<<(Ln*3*Dn)/256, 256, 0, stream>>>(bq, bk, bv, bqkv);
  ckern<<<Ln*Hn, 512, 0, stream>>>(gates, cbuf);
  gfill<<<(Ln*Hn*Tn*Tn)/256, 256, 0, stream>>>(cbuf, G);
  embed_kernel<<<Bn*Tn, 256, 0, stream>>>(tokens, embedp, pos, x);

  const int pref[8] = {0,512,1024,1280,1536,1664,1792,1856};
  const int MT = Bn*Tn;   // 8192

  for (int l=0; l<Ln; l++){
    // LN1 -> hbuf (bf16)
    ln_kernel<1><<<MT, 256, 0, stream>>>(x, ln1g + l*Dn, ln1b + l*Dn, hbuf);
    // QKV: one batched 128-tile GEMM, z = {q,k,v}
    gemm_big<1, 8192, Dn, Dn, (long)Ln*Dn*Dn, (long)Bn*Tn*Dn, Dn>
        <<<dim3(Dn/128, MT/128, 3), 256, 0, stream>>>(
        hbuf, WqT + (size_t)l*Dn*Dn, q, bqkv + (size_t)l*3*Dn);
    // pool K,V  (k,v dead afterwards; oT aliases k)
    pool_kernel<<<((long)Bn*1920*HDn + 255)/256, 256, 0, stream>>>(k, v, kp, vTp);

    for (int g=0; g<4; g++){
      int h0 = 2*g;
      int S  = Tn >> g;
      long koff = (long)Bn*HDn*pref[h0];
      // scores[zh,zb,t,s] = q_h . kp_h   (z = zh*16 + zb)
      gemm_kernel<0><<<dim3((S+127)/128, Tn/128, 32), 256, 0, stream>>>(
          q + h0*HDn, Dn, (long)Tn*Dn, (long)HDn,
          kp + koff, HDn, (long)S*HDn, (long)Bn*HDn*S,
          scoresA, S, (long)Tn*S, (long)Bn*Tn*S,
          nullptr, 0L, 4, 15,
          Tn, S, HDn);
      // softmax -> attn (bf16), 2*B*T rows, 4 rows/block
      switch (S){
        case 512: softmax_kernel<512><<<2*MT/4, 256, 0, stream>>>(scoresA, attnA); break;
        case 256: softmax_kernel<256><<<2*MT/4, 256, 0, stream>>>(scoresA, attnA); break;
        case 128: softmax_kernel<128><<<2*MT/4, 256, 0, stream>>>(scoresA, attnA); break;
        default:  softmax_kernel< 64><<<2*MT/4, 256, 0, stream>>>(scoresA, attnA); break;
      }
      // oT[h0+zh][zb][d][t] = sum_s vTp[h,b,d,s] * attn[zh,zb,t,s]
      gemm_kernel<1><<<dim3(Tn/128, HDn/128, 32), 256, 0, stream>>>(
          vTp + koff, S, (long)HDn*S, (long)Bn*HDn*S,
          attnA, S, (long)Tn*S, (long)Bn*Tn*S,
          oT + (size_t)h0*Bn*HDn*Tn, Tn, (long)HDn*Tn, (long)Bn*HDn*Tn,
          nullptr, 0L, 4, 15,
          HDn, Tn, S);
    }
    // spectral gating, all 8 heads in ONE launch (z = zh*16+zb, zh=head):
    // ao[zb, t, zh*128+d] = sum_s G[l,zh][t,s] * oT[zh][zb][d][s]
    gemm_kernel<1><<<dim3(1, Tn/128, 128), 256, 0, stream>>>(
        G + (size_t)(l*Hn)*Tn*Tn, Tn, 0L, (long)Tn*Tn,
        oT, Tn, (long)HDn*Tn, (long)Bn*HDn*Tn,
        ao, Dn, (long)Tn*Dn, (long)HDn,
        nullptr, 0L, 4, 15,
        Tn, HDn, Tn);
    // Wo projection + residual into x (fp32)
    gemm_big<3, 8192, Dn, Dn, 0L, 0L, 0>
        <<<dim3(Dn/128, MT/128, 1), 256, 0, stream>>>(
        ao, WoT + (size_t)l*Dn*Dn, x, bo + l*Dn);
    // LN2 -> hbuf
    ln_kernel<1><<<MT, 256, 0, stream>>>(x, ln2g + l*Dn, ln2b + l*Dn, hbuf);
    // FFN1: GELU(h@W1+b1) -> ff1 (bf16)   [scores/attn alias is dead now]
    gemm_big<2, 8192, Fn, Dn, 0L, 0L, 0>
        <<<dim3(Fn/128, MT/128, 1), 256, 0, stream>>>(
        hbuf, W1T + (size_t)l*Dn*Fn, ff1, b1 + l*Fn);
    // FFN2 + residual into x
    gemm_big<3, 8192, Dn, Fn, 0L, 0L, 0>
        <<<dim3(Dn/128, MT/128, 1), 256, 0, stream>>>(
        ff1, W2T + (size_t)l*Dn*Fn, x, b2 + l*Dn);
  }
  // final LN -> d_out (fp32)
  ln_kernel<0><<<MT, 256, 0, stream>>>(x, lnfg, lnfb, out);
}